// Round 5
// baseline (360.228 us; speedup 1.0000x reference)
//
#include <hip/hip_runtime.h>

#define NN 50000
#define EE 800000
#define KC 16        // histogram copies (one block each)
#define EPC (EE / KC)

typedef float f32x4 __attribute__((ext_vector_type(4)));
typedef short bf16x8 __attribute__((ext_vector_type(8)));
typedef unsigned short u16x8 __attribute__((ext_vector_type(8)));

__device__ __forceinline__ unsigned short f2bf(float f) {
  unsigned int u = __float_as_uint(f);
  u += 0x7fffu + ((u >> 16) & 1u);
  return (unsigned short)(u >> 16);
}
__device__ __forceinline__ float bf2f(unsigned short u) {
  return __uint_as_float(((unsigned int)u) << 16);
}

__device__ __forceinline__ void async_copy16(const void* g, void* l) {
  __builtin_amdgcn_global_load_lds(
      (const __attribute__((address_space(1))) unsigned int*)g,
      (__attribute__((address_space(3))) unsigned int*)l, 16, 0, 0);
}

// ---- strided-slot helpers: flat int index -> byte addr in a 512B/row region,
// using only the first 256B of each row (the +256 half holds hb/xb). ----
__device__ __forceinline__ float* degSlot(char* o, int c, int n) {
  const long i = (long)c * NN + n;  // [0, 800000) -> rows 0..12499
  return (float*)(o + (i >> 6) * 512 + (i & 63) * 4);
}
__device__ __forceinline__ int* cntSlot(char* o, int c, int n) {
  const long i = (long)EE + (long)c * NN + n;  // rows 12500..24999
  return (int*)(o + (i >> 6) * 512 + (i & 63) * 4);
}
__device__ __forceinline__ int* sbSlot(char* cB, int c, int n) {
  const long i = (long)c * NN + n;  // c-region rows 0..12499
  return (int*)(cB + (i >> 6) * 512 + (i & 63) * 4);
}
__device__ __forceinline__ unsigned short* rkSlot(char* cB, int e) {
  return (unsigned short*)(cB + (12500L + (e >> 7)) * 512 + (e & 127) * 2);
}

// ---------------- phase 1: edge-hist + buildB + h->bf16 + x->bf16 ----------------
__global__ __launch_bounds__(1024) void k_pre(
    const float* __restrict__ Wi, const float* __restrict__ Wf,
    const float* __restrict__ Wc, const float* __restrict__ Wo,
    const float* __restrict__ Ti, const float* __restrict__ Tf,
    const float* __restrict__ Tc, const float* __restrict__ To,
    unsigned short* __restrict__ bglob, const float* __restrict__ h,
    const float* __restrict__ x, char* __restrict__ outB,
    const int* __restrict__ src, const int* __restrict__ dst,
    const float* __restrict__ w) {
  const int b = blockIdx.x, tid = threadIdx.x;
  char* cB = outB + (long)NN * 512;
  if (b < KC) {
    // one block owns copy b -> workgroup-scope atomics stay in this XCD's L2
    const int base = b * EPC;
    for (int k = tid; k < EPC; k += 1024) {
      const int e = base + k;
      const int s = src[e], d = dst[e];
      __hip_atomic_fetch_add(degSlot(outB, b, s), w[e], __ATOMIC_RELAXED,
                             __HIP_MEMORY_SCOPE_WORKGROUP);
      const int r = __hip_atomic_fetch_add(cntSlot(outB, b, d), 1, __ATOMIC_RELAXED,
                                           __HIP_MEMORY_SCOPE_WORKGROUP);
      *rkSlot(cB, e) = (unsigned short)r;
    }
  } else if (b < KC + 32) {
    const int t = (b - KC) * 1024 + tid;  // 0..32767
    const int ks = t >> 11;
    const int cf = (t >> 6) & 31;
    const int lane = t & 63;
    const int wv = cf >> 3, hl = (cf >> 2) & 1, g = cf & 3;
    const int kg = lane >> 4, lm = lane & 15;
    const int hc = (wv * 2 + hl) * 16 + lm;
    const float* Wg = (g == 0) ? Wi : (g == 1) ? Wf : (g == 2) ? Wc : Wo;
    const float* Tg = (g == 0) ? Ti : (g == 1) ? Tf : (g == 2) ? Tc : To;
    u16x8 out;
#pragma unroll
    for (int dk = 0; dk < 8; ++dk) {
      const int k = ks * 32 + kg * 8 + dk;
      const int kb = k >> 7, r = k & 127;
      const float v = (kb == 0) ? Wg[r * 128 + hc] : Tg[(kb - 1) * 16384 + r * 128 + hc];
      out[dk] = f2bf(v);
    }
    *(u16x8*)(bglob + t * 8) = out;
  } else if (b < KC + 32 + 782) {
    const int i = (b - (KC + 32)) * 1024 + tid;  // 8-f32 chunks of h
    if (i < 100000 * 8) {
      const float* hp = h + i * 8;
      const f32x4 v0 = *(const f32x4*)hp;
      const f32x4 v1 = *(const f32x4*)(hp + 4);
      u16x8 o;
#pragma unroll
      for (int e = 0; e < 4; ++e) o[e] = f2bf(v0[e]);
#pragma unroll
      for (int e = 0; e < 4; ++e) o[e + 4] = f2bf(v1[e]);
      *(u16x8*)(outB + (i >> 4) * 512 + 256 + (i & 15) * 16) = o;
    }
  } else {
    const int i = (b - (KC + 32 + 782)) * 1024 + tid;
    if (i < 100000 * 8) {
      const float* xp = x + i * 8;
      const f32x4 v0 = *(const f32x4*)xp;
      const f32x4 v1 = *(const f32x4*)(xp + 4);
      u16x8 o;
#pragma unroll
      for (int e = 0; e < 4; ++e) o[e] = f2bf(v0[e]);
#pragma unroll
      for (int e = 0; e < 4; ++e) o[e + 4] = f2bf(v1[e]);
      *(u16x8*)(cB + (i >> 4) * 512 + 256 + (i & 15) * 16) = o;
    }
  }
}

// ---------------- scan machinery ----------------
__device__ __forceinline__ int block_scan_excl_256(int v, int* total) {
  __shared__ int wsum[4];
  const int tid = threadIdx.x;
  const int lane = tid & 63, wv = tid >> 6;
  int x = v;
#pragma unroll
  for (int d = 1; d < 64; d <<= 1) {
    const int y = __shfl_up(x, d, 64);
    if (lane >= d) x += y;
  }
  if (lane == 63) wsum[wv] = x;
  __syncthreads();
  int pre = 0, tot = 0;
#pragma unroll
  for (int u = 0; u < 4; ++u) {
    const int s = wsum[u];
    pre += (u < wv) ? s : 0;
    tot += s;
  }
  *total = tot;
  return pre + x - v;
}

// reduce deg copies -> dinv; running-sum cnt copies -> segbase + cnt_tot; block sums
__global__ void k_phase2(char* __restrict__ outB, float* __restrict__ dinv,
                         int* __restrict__ wscnt, int* __restrict__ bsum) {
  char* cB = outB + (long)NN * 512;
  const int i = blockIdx.x * 256 + threadIdx.x;
  int run = 0;
  if (i < NN) {
    float s = 0.f;
#pragma unroll
    for (int c = 0; c < KC; ++c) s += *degSlot(outB, c, i);
    dinv[i] = (s > 0.f) ? rsqrtf(fmaxf(s, 1e-30f)) : 0.f;
#pragma unroll
    for (int c = 0; c < KC; ++c) {
      *sbSlot(cB, c, i) = run;
      run += *cntSlot(outB, c, i);
    }
    wscnt[i] = run;
  }
  int tot;
  block_scan_excl_256(run, &tot);
  if (threadIdx.x == 0) bsum[blockIdx.x] = tot;
}

__global__ void k_scan2(const int* __restrict__ bsum, int* __restrict__ boff,
                        const int nb) {
  const int t = threadIdx.x;
  const int v = (t < nb) ? bsum[t] : 0;
  int tot;
  const int excl = block_scan_excl_256(v, &tot);
  if (t <= nb) boff[t] = excl;
}

__global__ void k_scan3(const int* __restrict__ cnt, const int* __restrict__ boff,
                        int* __restrict__ off) {
  const int i = blockIdx.x * 256 + threadIdx.x;
  const int v = (i < NN) ? cnt[i] : 0;
  int tot;
  const int excl = block_scan_excl_256(v, &tot) + boff[blockIdx.x];
  if (i < NN) off[i] = excl;
  if (i == NN) off[NN] = excl;
}

// atomic-free CSR fill: p = off[d] + segbase[copy][d] + rank[e]
__global__ void k_edge2(const int* __restrict__ src, const int* __restrict__ dst,
                        const float* __restrict__ w, const float* __restrict__ dinv,
                        const int* __restrict__ off, char* __restrict__ outB,
                        int2* __restrict__ ed) {
  const int e = blockIdx.x * blockDim.x + threadIdx.x;
  if (e >= EE) return;
  char* cB = outB + (long)NN * 512;
  const int s = src[e], d = dst[e];
  const int c = e / EPC;
  const int p = off[d] + *sbSlot(cB, c, d) + (int)*rkSlot(cB, e);
  int2 rec;
  rec.x = s;
  rec.y = __float_as_int(-w[e] * dinv[s] * dinv[d]);
  ed[p] = rec;
}

// ---------------- sparse gather (bf16 rows, 1 wave per node) ----------------
__global__ __launch_bounds__(256) void k_gather(
    const char* __restrict__ vinB, const char* __restrict__ vsubB, const float alpha,
    const int* __restrict__ off, const int2* __restrict__ ed, char* __restrict__ voutB) {
  const int wid = threadIdx.x >> 6, lane = threadIdx.x & 63;
  const int node = blockIdx.x * 4 + wid;
  const int p0 = off[node], p1 = off[node + 1];
  const int lb = lane * 4;
  float ax0 = 0.f, ay0 = 0.f, ax1 = 0.f, ay1 = 0.f;
  float ax2 = 0.f, ay2 = 0.f, ax3 = 0.f, ay3 = 0.f;
  int p = p0;
  for (; p + 3 < p1; p += 4) {
    const int2 e0 = ed[p], e1 = ed[p + 1], e2 = ed[p + 2], e3 = ed[p + 3];
    const unsigned v0 = *(const unsigned*)(vinB + e0.x * 512 + lb);
    const unsigned v1 = *(const unsigned*)(vinB + e1.x * 512 + lb);
    const unsigned v2 = *(const unsigned*)(vinB + e2.x * 512 + lb);
    const unsigned v3 = *(const unsigned*)(vinB + e3.x * 512 + lb);
    const float w0 = __int_as_float(e0.y), w1 = __int_as_float(e1.y);
    const float w2 = __int_as_float(e2.y), w3 = __int_as_float(e3.y);
    ax0 = fmaf(w0, bf2f((unsigned short)v0), ax0);
    ay0 = fmaf(w0, bf2f((unsigned short)(v0 >> 16)), ay0);
    ax1 = fmaf(w1, bf2f((unsigned short)v1), ax1);
    ay1 = fmaf(w1, bf2f((unsigned short)(v1 >> 16)), ay1);
    ax2 = fmaf(w2, bf2f((unsigned short)v2), ax2);
    ay2 = fmaf(w2, bf2f((unsigned short)(v2 >> 16)), ay2);
    ax3 = fmaf(w3, bf2f((unsigned short)v3), ax3);
    ay3 = fmaf(w3, bf2f((unsigned short)(v3 >> 16)), ay3);
  }
  for (; p < p1; ++p) {
    const int2 e0 = ed[p];
    const unsigned v0 = *(const unsigned*)(vinB + e0.x * 512 + lb);
    const float w0 = __int_as_float(e0.y);
    ax0 = fmaf(w0, bf2f((unsigned short)v0), ax0);
    ay0 = fmaf(w0, bf2f((unsigned short)(v0 >> 16)), ay0);
  }
  float rx = alpha * ((ax0 + ax1) + (ax2 + ax3));
  float ry = alpha * ((ay0 + ay1) + (ay2 + ay3));
  if (vsubB) {
    const unsigned s = *(const unsigned*)(vsubB + node * 512 + lb);
    rx -= bf2f((unsigned short)s);
    ry -= bf2f((unsigned short)(s >> 16));
  }
  const unsigned ow = (unsigned)f2bf(rx) | ((unsigned)f2bf(ry) << 16);
  *(unsigned*)(voutB + node * 512 + lb) = ow;
}

// ---------------- dense stage (as round 4) ----------------
__global__ __launch_bounds__(256, 2) void k_gemm(
    const char* __restrict__ outB, const unsigned short* __restrict__ bglob,
    const float* __restrict__ c_prev,
    const float* __restrict__ b_i, const float* __restrict__ b_f,
    const float* __restrict__ b_c, const float* __restrict__ b_o,
    const float* __restrict__ w_ci, const float* __restrict__ w_cf,
    const float* __restrict__ w_co, float* __restrict__ h_out,
    float* __restrict__ c_out) {
  __shared__ char lds[2][4096];
  const int tid = threadIdx.x;
  const int lane = tid & 63;
  const int wid = tid >> 6;
  const int kg = lane >> 4;
  const int lm = lane & 15;
  const int m0 = blockIdx.x * 64;

  const char* hB = outB;                   // +0: tx1b, +256: hb
  const char* cB = outB + (long)NN * 512;  // +0: tx2b, +256: xb

  const int srow0 = m0 + wid * 16 + lm;
  const long srow = (srow0 < NN) ? srow0 : (NN - 1);
  const int schunk = kg * 16;

  f32x4 acc[32];
#pragma unroll
  for (int i = 0; i < 32; ++i) acc[i] = (f32x4){0.f, 0.f, 0.f, 0.f};

  auto stage = [&](int ks, int buf) {
    const char* base = (ks < 4) ? (cB + 256) : (ks < 8) ? (hB + 256) : (ks < 12) ? hB : cB;
    async_copy16(base + srow * 512 + (ks & 3) * 64 + schunk, &lds[buf][tid * 16]);
  };

  bf16x8 br0[8], br1[8];
  auto loadB = [&](int ks, bf16x8* bb) {
    const unsigned short* fp = bglob + ((ks * 32 + wid * 8) * 64 + lane) * 8;
#pragma unroll
    for (int i = 0; i < 8; ++i) bb[i] = *(const bf16x8*)(fp + i * 512);
  };

  stage(0, 0);
  loadB(0, br0);
  __syncthreads();

#pragma unroll
  for (int ks = 0; ks < 16; ++ks) {
    const int buf = ks & 1;
    if (ks < 15) {
      stage(ks + 1, buf ^ 1);
      loadB(ks + 1, (ks & 1) ? br0 : br1);
    }
    bf16x8 a[4];
#pragma unroll
    for (int rf = 0; rf < 4; ++rf)
      a[rf] = *(const bf16x8*)(&lds[buf][rf * 1024 + lane * 16]);
    const bf16x8* br = (ks & 1) ? br1 : br0;
#pragma unroll
    for (int rf = 0; rf < 4; ++rf)
#pragma unroll
      for (int i = 0; i < 8; ++i)
        acc[rf * 8 + i] =
            __builtin_amdgcn_mfma_f32_16x16x32_bf16(a[rf], br[i], acc[rf * 8 + i], 0, 0, 0);
    __syncthreads();
  }

#pragma unroll
  for (int hl = 0; hl < 2; ++hl) {
    const int hc = (wid * 2 + hl) * 16 + lm;
    const float bi = b_i[hc], bfv = b_f[hc], bc = b_c[hc], bo = b_o[hc];
    const float wci = w_ci[hc], wcf = w_cf[hc], wco = w_co[hc];
#pragma unroll
    for (int rf = 0; rf < 4; ++rf) {
#pragma unroll
      for (int reg = 0; reg < 4; ++reg) {
        const int node = m0 + rf * 16 + kg * 4 + reg;
        if (node < NN) {
          const float cp = c_prev[node * 128 + hc];
          const float pi = acc[rf * 8 + hl * 4 + 0][reg] + bi + wci * cp;
          const float pf = acc[rf * 8 + hl * 4 + 1][reg] + bfv + wcf * cp;
          const float pc = acc[rf * 8 + hl * 4 + 2][reg] + bc;
          const float po = acc[rf * 8 + hl * 4 + 3][reg] + bo;
          const float ig = 1.f / (1.f + __expf(-pi));
          const float fg = 1.f / (1.f + __expf(-pf));
          const float ct = fg * cp + ig * tanhf(pc);
          const float og = 1.f / (1.f + __expf(-(po + wco * ct)));
          h_out[node * 128 + hc] = og * tanhf(ct);
          c_out[node * 128 + hc] = ct;
        }
      }
    }
  }
}

// ---------------- launcher ----------------

extern "C" void kernel_launch(void* const* d_in, const int* in_sizes, int n_in,
                              void* d_out, int out_size, void* d_ws, size_t ws_size,
                              hipStream_t stream) {
  const float* x_t    = (const float*)d_in[0];
  const float* h_prev = (const float*)d_in[1];
  const float* c_prev = (const float*)d_in[2];
  const float* ew     = (const float*)d_in[3];
  const int*   eidx   = (const int*)d_in[4];
  const float* Wi = (const float*)d_in[5];
  const float* Wf = (const float*)d_in[6];
  const float* Wc = (const float*)d_in[7];
  const float* Wo = (const float*)d_in[8];
  const float* Ti = (const float*)d_in[9];
  const float* Tf = (const float*)d_in[10];
  const float* Tc = (const float*)d_in[11];
  const float* To = (const float*)d_in[12];
  const float* bi = (const float*)d_in[13];
  const float* bf = (const float*)d_in[14];
  const float* bc = (const float*)d_in[15];
  const float* bo = (const float*)d_in[16];
  const float* wci = (const float*)d_in[17];
  const float* wcf = (const float*)d_in[18];
  const float* wco = (const float*)d_in[19];

  char* ws = (char*)d_ws;
  float* dinv  = (float*)(ws + 0);        // 200192
  int*   wscnt = (int*)(ws + 200192);     // 200192
  int*   off   = (int*)(ws + 400384);     // 200704
  int*   bsum  = (int*)(ws + 601088);     // 1024
  int*   boff  = (int*)(ws + 602112);     // 1024
  int2*  ed    = (int2*)(ws + 603136);    // 6400000
  unsigned short* bglob = (unsigned short*)(ws + 7003136);  // 524288

  char* outB = (char*)d_out;  // h-rows: [tx1b/hist | hb]; c-rows: [tx2b/segbase/rank | xb]
  float* h_out = (float*)d_out;
  float* c_out = h_out + (long)NN * 128;

  const int* esrc = eidx;
  const int* edst = eidx + EE;

  // zero the 16 deg/cnt histogram copies (rows 0..24999 of the h-region)
  hipMemsetAsync(d_out, 0, 12800000, stream);

  k_pre<<<KC + 32 + 782 + 782, 1024, 0, stream>>>(
      Wi, Wf, Wc, Wo, Ti, Tf, Tc, To, bglob, h_prev, x_t, outB, esrc, edst, ew);
  k_phase2<<<196, 256, 0, stream>>>(outB, dinv, wscnt, bsum);
  k_scan2<<<1, 256, 0, stream>>>(bsum, boff, 196);
  k_scan3<<<196, 256, 0, stream>>>(wscnt, boff, off);
  k_edge2<<<3125, 256, 0, stream>>>(esrc, edst, ew, dinv, off, outB, ed);
  k_gather<<<12500, 256, 0, stream>>>(outB + 256, nullptr, 1.f, off, ed, outB);
  k_gather<<<12500, 256, 0, stream>>>(outB, outB + 256, 2.f, off, ed,
                                      outB + (long)NN * 512);
  k_gemm<<<782, 256, 0, stream>>>(outB, bglob, c_prev,
                                  bi, bf, bc, bo, wci, wcf, wco, h_out, c_out);
}

// Round 6
// 270.520 us; speedup vs baseline: 1.3316x; 1.3316x over previous
//
#include <hip/hip_runtime.h>

#define NN 50000
#define EE 800000
#define KC 32          // histogram copies (one hist block each)
#define EPC (EE / KC)  // 25000 edges per hist block

typedef float f32x4 __attribute__((ext_vector_type(4)));
typedef short bf16x8 __attribute__((ext_vector_type(8)));
typedef unsigned short u16x8 __attribute__((ext_vector_type(8)));

__device__ __forceinline__ unsigned short f2bf(float f) {
  unsigned int u = __float_as_uint(f);
  u += 0x7fffu + ((u >> 16) & 1u);
  return (unsigned short)(u >> 16);
}
__device__ __forceinline__ float bf2f(unsigned short u) {
  return __uint_as_float(((unsigned int)u) << 16);
}

__device__ __forceinline__ void async_copy16(const void* g, void* l) {
  __builtin_amdgcn_global_load_lds(
      (const __attribute__((address_space(1))) unsigned int*)g,
      (__attribute__((address_space(3))) unsigned int*)l, 16, 0, 0);
}

// ---- flat scratch in the first 256B of each 512B d_out row ----
// 4B slots: 64/row ; 2B slots: 128/row
__device__ __forceinline__ float* hslot4(char* o, long i) {
  return (float*)(o + (i >> 6) * 512 + (i & 63) * 4);
}
__device__ __forceinline__ unsigned short* hslot2(char* o, long j) {
  return (unsigned short*)(o + (j >> 7) * 512 + (j & 127) * 2);
}
// h-region map: deg copies slots4 [0, 1.6M) ; cnt copies slots2 [3.2M, 4.8M);
// rank slots2 [4.8M, 5.6M).  c-region map: segbase slots4 [0, 1.6M).

// ---------------- phase 1: LDS-histograms + buildB + h->bf16 + x->bf16 ----------------
__global__ __launch_bounds__(1024) void k_pre(
    const float* __restrict__ Wi, const float* __restrict__ Wf,
    const float* __restrict__ Wc, const float* __restrict__ Wo,
    const float* __restrict__ Ti, const float* __restrict__ Tf,
    const float* __restrict__ Tc, const float* __restrict__ To,
    unsigned short* __restrict__ bglob, const float* __restrict__ h,
    const float* __restrict__ x, char* __restrict__ outB,
    const int* __restrict__ src, const int* __restrict__ dst,
    const float* __restrict__ w) {
  const int b = blockIdx.x, tid = threadIdx.x;
  char* cB = outB + (long)NN * 512;
  if (b < KC) {
    __shared__ unsigned hist[12500];  // 50 KB
    const int base = b * EPC;
    // ---- cnt (packed 2 x u16 bins) + rank, 2 node-range passes ----
#pragma unroll
    for (int P = 0; P < 2; ++P) {
      for (int j = tid; j < 12500; j += 1024) hist[j] = 0u;
      __syncthreads();
      const int lo = P * 25000;
      for (int k = tid; k < EPC; k += 1024) {
        const int e = base + k;
        const int d = dst[e];
        if (d >= lo && d < lo + 25000) {
          const int l = d - lo;
          const int sh = (l & 1) * 16;
          const unsigned old = atomicAdd(&hist[l >> 1], 1u << sh);
          *hslot2(outB, 4800000L + e) = (unsigned short)((old >> sh) & 0xffffu);
        }
      }
      __syncthreads();
      for (int j = tid; j < 12500; j += 1024) {
        const long idx2 = 3200000L + (long)b * NN + lo + 2 * j;  // even
        *(unsigned*)((char*)outB + (idx2 >> 7) * 512 + (idx2 & 127) * 2) = hist[j];
      }
      __syncthreads();
    }
    // ---- deg (float bins), 4 node-range passes ----
#pragma unroll
    for (int Q = 0; Q < 4; ++Q) {
      for (int j = tid; j < 12500; j += 1024) hist[j] = 0u;
      __syncthreads();
      const int lo = Q * 12500;
      for (int k = tid; k < EPC; k += 1024) {
        const int e = base + k;
        const int s = src[e];
        if (s >= lo && s < lo + 12500)
          atomicAdd((float*)&hist[s - lo], w[e]);
      }
      __syncthreads();
      for (int j = tid; j < 12500; j += 1024)
        *hslot4(outB, (long)b * NN + lo + j) = ((float*)hist)[j];
      __syncthreads();
    }
  } else if (b < KC + 32) {
    // buildB: fragment-native (as before)
    const int t = (b - KC) * 1024 + tid;  // 0..32767
    const int ks = t >> 11;
    const int cf = (t >> 6) & 31;
    const int lane = t & 63;
    const int wv = cf >> 3, hl = (cf >> 2) & 1, g = cf & 3;
    const int kg = lane >> 4, lm = lane & 15;
    const int hc = (wv * 2 + hl) * 16 + lm;
    const float* Wg = (g == 0) ? Wi : (g == 1) ? Wf : (g == 2) ? Wc : Wo;
    const float* Tg = (g == 0) ? Ti : (g == 1) ? Tf : (g == 2) ? Tc : To;
    u16x8 out;
#pragma unroll
    for (int dk = 0; dk < 8; ++dk) {
      const int k = ks * 32 + kg * 8 + dk;
      const int kb = k >> 7, r = k & 127;
      const float v = (kb == 0) ? Wg[r * 128 + hc] : Tg[(kb - 1) * 16384 + r * 128 + hc];
      out[dk] = f2bf(v);
    }
    *(u16x8*)(bglob + t * 8) = out;
  } else if (b < KC + 32 + 782) {
    const int i = (b - (KC + 32)) * 1024 + tid;  // 8-f32 chunks of h
    if (i < 100000 * 8) {
      const float* hp = h + i * 8;
      const f32x4 v0 = *(const f32x4*)hp;
      const f32x4 v1 = *(const f32x4*)(hp + 4);
      u16x8 o;
#pragma unroll
      for (int e = 0; e < 4; ++e) o[e] = f2bf(v0[e]);
#pragma unroll
      for (int e = 0; e < 4; ++e) o[e + 4] = f2bf(v1[e]);
      *(u16x8*)(outB + (i >> 4) * 512 + 256 + (i & 15) * 16) = o;
    }
  } else {
    const int i = (b - (KC + 32 + 782)) * 1024 + tid;
    if (i < 100000 * 8) {
      const float* xp = x + i * 8;
      const f32x4 v0 = *(const f32x4*)xp;
      const f32x4 v1 = *(const f32x4*)(xp + 4);
      u16x8 o;
#pragma unroll
      for (int e = 0; e < 4; ++e) o[e] = f2bf(v0[e]);
#pragma unroll
      for (int e = 0; e < 4; ++e) o[e + 4] = f2bf(v1[e]);
      *(u16x8*)(cB + (i >> 4) * 512 + 256 + (i & 15) * 16) = o;
    }
  }
}

// ---------------- scan machinery ----------------
__device__ __forceinline__ int block_scan_excl_256(int v, int* total) {
  __shared__ int wsum[4];
  const int tid = threadIdx.x;
  const int lane = tid & 63, wv = tid >> 6;
  int x = v;
#pragma unroll
  for (int d = 1; d < 64; d <<= 1) {
    const int y = __shfl_up(x, d, 64);
    if (lane >= d) x += y;
  }
  if (lane == 63) wsum[wv] = x;
  __syncthreads();
  int pre = 0, tot = 0;
#pragma unroll
  for (int u = 0; u < 4; ++u) {
    const int s = wsum[u];
    pre += (u < wv) ? s : 0;
    tot += s;
  }
  *total = tot;
  return pre + x - v;
}

// reduce deg copies -> dinv; running-sum cnt copies -> segbase (c-region) + wscnt
__global__ void k_phase2(char* __restrict__ outB, float* __restrict__ dinv,
                         int* __restrict__ wscnt, int* __restrict__ bsum) {
  char* cB = outB + (long)NN * 512;
  const int i = blockIdx.x * 256 + threadIdx.x;
  int run = 0;
  if (i < NN) {
    float s = 0.f;
#pragma unroll
    for (int c = 0; c < KC; ++c) s += *hslot4(outB, (long)c * NN + i);
    dinv[i] = (s > 0.f) ? rsqrtf(fmaxf(s, 1e-30f)) : 0.f;
#pragma unroll
    for (int c = 0; c < KC; ++c) {
      *(int*)hslot4(cB, (long)c * NN + i) = run;
      run += (int)*hslot2(outB, 3200000L + (long)c * NN + i);
    }
    wscnt[i] = run;
  }
  int tot;
  block_scan_excl_256(run, &tot);
  if (threadIdx.x == 0) bsum[blockIdx.x] = tot;
}

__global__ void k_scan2(const int* __restrict__ bsum, int* __restrict__ boff,
                        const int nb) {
  const int t = threadIdx.x;
  const int v = (t < nb) ? bsum[t] : 0;
  int tot;
  const int excl = block_scan_excl_256(v, &tot);
  if (t <= nb) boff[t] = excl;
}

__global__ void k_scan3(const int* __restrict__ cnt, const int* __restrict__ boff,
                        int* __restrict__ off) {
  const int i = blockIdx.x * 256 + threadIdx.x;
  const int v = (i < NN) ? cnt[i] : 0;
  int tot;
  const int excl = block_scan_excl_256(v, &tot) + boff[blockIdx.x];
  if (i < NN) off[i] = excl;
  if (i == NN) off[NN] = excl;
}

// atomic-free CSR fill: p = off[d] + segbase[copy][d] + rank[e]
__global__ void k_edge2(const int* __restrict__ src, const int* __restrict__ dst,
                        const float* __restrict__ w, const float* __restrict__ dinv,
                        const int* __restrict__ off, char* __restrict__ outB,
                        int2* __restrict__ ed) {
  const int e = blockIdx.x * blockDim.x + threadIdx.x;
  if (e >= EE) return;
  char* cB = outB + (long)NN * 512;
  const int s = src[e], d = dst[e];
  const int c = e / EPC;
  const int p = off[d] + *(int*)hslot4(cB, (long)c * NN + d) +
                (int)*hslot2(outB, 4800000L + e);
  int2 rec;
  rec.x = s;
  rec.y = __float_as_int(-w[e] * dinv[s] * dinv[d]);
  ed[p] = rec;
}

// ---------------- sparse gather (bf16 rows, 1 wave per node) ----------------
__global__ __launch_bounds__(256) void k_gather(
    const char* __restrict__ vinB, const char* __restrict__ vsubB, const float alpha,
    const int* __restrict__ off, const int2* __restrict__ ed, char* __restrict__ voutB) {
  const int wid = threadIdx.x >> 6, lane = threadIdx.x & 63;
  const int node = blockIdx.x * 4 + wid;
  const int p0 = off[node], p1 = off[node + 1];
  const int lb = lane * 4;
  float ax0 = 0.f, ay0 = 0.f, ax1 = 0.f, ay1 = 0.f;
  float ax2 = 0.f, ay2 = 0.f, ax3 = 0.f, ay3 = 0.f;
  int p = p0;
  for (; p + 3 < p1; p += 4) {
    const int2 e0 = ed[p], e1 = ed[p + 1], e2 = ed[p + 2], e3 = ed[p + 3];
    const unsigned v0 = *(const unsigned*)(vinB + e0.x * 512 + lb);
    const unsigned v1 = *(const unsigned*)(vinB + e1.x * 512 + lb);
    const unsigned v2 = *(const unsigned*)(vinB + e2.x * 512 + lb);
    const unsigned v3 = *(const unsigned*)(vinB + e3.x * 512 + lb);
    const float w0 = __int_as_float(e0.y), w1 = __int_as_float(e1.y);
    const float w2 = __int_as_float(e2.y), w3 = __int_as_float(e3.y);
    ax0 = fmaf(w0, bf2f((unsigned short)v0), ax0);
    ay0 = fmaf(w0, bf2f((unsigned short)(v0 >> 16)), ay0);
    ax1 = fmaf(w1, bf2f((unsigned short)v1), ax1);
    ay1 = fmaf(w1, bf2f((unsigned short)(v1 >> 16)), ay1);
    ax2 = fmaf(w2, bf2f((unsigned short)v2), ax2);
    ay2 = fmaf(w2, bf2f((unsigned short)(v2 >> 16)), ay2);
    ax3 = fmaf(w3, bf2f((unsigned short)v3), ax3);
    ay3 = fmaf(w3, bf2f((unsigned short)(v3 >> 16)), ay3);
  }
  for (; p < p1; ++p) {
    const int2 e0 = ed[p];
    const unsigned v0 = *(const unsigned*)(vinB + e0.x * 512 + lb);
    const float w0 = __int_as_float(e0.y);
    ax0 = fmaf(w0, bf2f((unsigned short)v0), ax0);
    ay0 = fmaf(w0, bf2f((unsigned short)(v0 >> 16)), ay0);
  }
  float rx = alpha * ((ax0 + ax1) + (ax2 + ax3));
  float ry = alpha * ((ay0 + ay1) + (ay2 + ay3));
  if (vsubB) {
    const unsigned s = *(const unsigned*)(vsubB + node * 512 + lb);
    rx -= bf2f((unsigned short)s);
    ry -= bf2f((unsigned short)(s >> 16));
  }
  const unsigned ow = (unsigned)f2bf(rx) | ((unsigned)f2bf(ry) << 16);
  *(unsigned*)(voutB + node * 512 + lb) = ow;
}

// ---------------- dense stage (as round 4/5) ----------------
__global__ __launch_bounds__(256, 2) void k_gemm(
    const char* __restrict__ outB, const unsigned short* __restrict__ bglob,
    const float* __restrict__ c_prev,
    const float* __restrict__ b_i, const float* __restrict__ b_f,
    const float* __restrict__ b_c, const float* __restrict__ b_o,
    const float* __restrict__ w_ci, const float* __restrict__ w_cf,
    const float* __restrict__ w_co, float* __restrict__ h_out,
    float* __restrict__ c_out) {
  __shared__ char lds[2][4096];
  const int tid = threadIdx.x;
  const int lane = tid & 63;
  const int wid = tid >> 6;
  const int kg = lane >> 4;
  const int lm = lane & 15;
  const int m0 = blockIdx.x * 64;

  const char* hB = outB;                   // +0: tx1b, +256: hb
  const char* cB = outB + (long)NN * 512;  // +0: tx2b, +256: xb

  const int srow0 = m0 + wid * 16 + lm;
  const long srow = (srow0 < NN) ? srow0 : (NN - 1);
  const int schunk = kg * 16;

  f32x4 acc[32];
#pragma unroll
  for (int i = 0; i < 32; ++i) acc[i] = (f32x4){0.f, 0.f, 0.f, 0.f};

  auto stage = [&](int ks, int buf) {
    const char* base = (ks < 4) ? (cB + 256) : (ks < 8) ? (hB + 256) : (ks < 12) ? hB : cB;
    async_copy16(base + srow * 512 + (ks & 3) * 64 + schunk, &lds[buf][tid * 16]);
  };

  bf16x8 br0[8], br1[8];
  auto loadB = [&](int ks, bf16x8* bb) {
    const unsigned short* fp = bglob + ((ks * 32 + wid * 8) * 64 + lane) * 8;
#pragma unroll
    for (int i = 0; i < 8; ++i) bb[i] = *(const bf16x8*)(fp + i * 512);
  };

  stage(0, 0);
  loadB(0, br0);
  __syncthreads();

#pragma unroll
  for (int ks = 0; ks < 16; ++ks) {
    const int buf = ks & 1;
    if (ks < 15) {
      stage(ks + 1, buf ^ 1);
      loadB(ks + 1, (ks & 1) ? br0 : br1);
    }
    bf16x8 a[4];
#pragma unroll
    for (int rf = 0; rf < 4; ++rf)
      a[rf] = *(const bf16x8*)(&lds[buf][rf * 1024 + lane * 16]);
    const bf16x8* br = (ks & 1) ? br1 : br0;
#pragma unroll
    for (int rf = 0; rf < 4; ++rf)
#pragma unroll
      for (int i = 0; i < 8; ++i)
        acc[rf * 8 + i] =
            __builtin_amdgcn_mfma_f32_16x16x32_bf16(a[rf], br[i], acc[rf * 8 + i], 0, 0, 0);
    __syncthreads();
  }

#pragma unroll
  for (int hl = 0; hl < 2; ++hl) {
    const int hc = (wid * 2 + hl) * 16 + lm;
    const float bi = b_i[hc], bfv = b_f[hc], bc = b_c[hc], bo = b_o[hc];
    const float wci = w_ci[hc], wcf = w_cf[hc], wco = w_co[hc];
#pragma unroll
    for (int rf = 0; rf < 4; ++rf) {
#pragma unroll
      for (int reg = 0; reg < 4; ++reg) {
        const int node = m0 + rf * 16 + kg * 4 + reg;
        if (node < NN) {
          const float cp = c_prev[node * 128 + hc];
          const float pi = acc[rf * 8 + hl * 4 + 0][reg] + bi + wci * cp;
          const float pf = acc[rf * 8 + hl * 4 + 1][reg] + bfv + wcf * cp;
          const float pc = acc[rf * 8 + hl * 4 + 2][reg] + bc;
          const float po = acc[rf * 8 + hl * 4 + 3][reg] + bo;
          const float ig = 1.f / (1.f + __expf(-pi));
          const float fg = 1.f / (1.f + __expf(-pf));
          const float ct = fg * cp + ig * tanhf(pc);
          const float og = 1.f / (1.f + __expf(-(po + wco * ct)));
          h_out[node * 128 + hc] = og * tanhf(ct);
          c_out[node * 128 + hc] = ct;
        }
      }
    }
  }
}

// ---------------- launcher ----------------

extern "C" void kernel_launch(void* const* d_in, const int* in_sizes, int n_in,
                              void* d_out, int out_size, void* d_ws, size_t ws_size,
                              hipStream_t stream) {
  const float* x_t    = (const float*)d_in[0];
  const float* h_prev = (const float*)d_in[1];
  const float* c_prev = (const float*)d_in[2];
  const float* ew     = (const float*)d_in[3];
  const int*   eidx   = (const int*)d_in[4];
  const float* Wi = (const float*)d_in[5];
  const float* Wf = (const float*)d_in[6];
  const float* Wc = (const float*)d_in[7];
  const float* Wo = (const float*)d_in[8];
  const float* Ti = (const float*)d_in[9];
  const float* Tf = (const float*)d_in[10];
  const float* Tc = (const float*)d_in[11];
  const float* To = (const float*)d_in[12];
  const float* bi = (const float*)d_in[13];
  const float* bf = (const float*)d_in[14];
  const float* bc = (const float*)d_in[15];
  const float* bo = (const float*)d_in[16];
  const float* wci = (const float*)d_in[17];
  const float* wcf = (const float*)d_in[18];
  const float* wco = (const float*)d_in[19];

  char* ws = (char*)d_ws;
  float* dinv  = (float*)(ws + 0);        // 200192
  int*   wscnt = (int*)(ws + 200192);     // 200192
  int*   off   = (int*)(ws + 400384);     // 200704
  int*   bsum  = (int*)(ws + 601088);     // 1024
  int*   boff  = (int*)(ws + 602112);     // 1024
  int2*  ed    = (int2*)(ws + 603136);    // 6400000
  unsigned short* bglob = (unsigned short*)(ws + 7003136);  // 524288

  char* outB = (char*)d_out;  // h-rows: [scratch | hb]; c-rows: [scratch | xb]
  float* h_out = (float*)d_out;
  float* c_out = h_out + (long)NN * 128;

  const int* esrc = eidx;
  const int* edst = eidx + EE;

  k_pre<<<KC + 32 + 782 + 782, 1024, 0, stream>>>(
      Wi, Wf, Wc, Wo, Ti, Tf, Tc, To, bglob, h_prev, x_t, outB, esrc, edst, ew);
  k_phase2<<<196, 256, 0, stream>>>(outB, dinv, wscnt, bsum);
  k_scan2<<<1, 256, 0, stream>>>(bsum, boff, 196);
  k_scan3<<<196, 256, 0, stream>>>(wscnt, boff, off);
  k_edge2<<<3125, 256, 0, stream>>>(esrc, edst, ew, dinv, off, outB, ed);
  k_gather<<<12500, 256, 0, stream>>>(outB + 256, nullptr, 1.f, off, ed, outB);
  k_gather<<<12500, 256, 0, stream>>>(outB, outB + 256, 2.f, off, ed,
                                      outB + (long)NN * 512);
  k_gemm<<<782, 256, 0, stream>>>(outB, bglob, c_prev,
                                  bi, bf, bc, bo, wci, wcf, wco, h_out, c_out);
}

// Round 7
// 226.664 us; speedup vs baseline: 1.5893x; 1.1935x over previous
//
#include <hip/hip_runtime.h>

#define NN 50000
#define EE 800000
#define KC 64          // histogram copies (one hist block each)
#define EPC (EE / KC)  // 12500 edges per hist block
#define DEG_SCALE 4096.0f

typedef float f32x4 __attribute__((ext_vector_type(4)));
typedef short bf16x8 __attribute__((ext_vector_type(8)));
typedef unsigned short u16x8 __attribute__((ext_vector_type(8)));

__device__ __forceinline__ unsigned short f2bf(float f) {
  unsigned int u = __float_as_uint(f);
  u += 0x7fffu + ((u >> 16) & 1u);
  return (unsigned short)(u >> 16);
}
__device__ __forceinline__ float bf2f(unsigned short u) {
  return __uint_as_float(((unsigned int)u) << 16);
}

__device__ __forceinline__ void async_copy16(const void* g, void* l) {
  __builtin_amdgcn_global_load_lds(
      (const __attribute__((address_space(1))) unsigned int*)g,
      (__attribute__((address_space(3))) unsigned int*)l, 16, 0, 0);
}

// ---- u16-slot scratch in the first 256B of each 512B d_out row ----
// u16 slot j -> byte (j>>7)*512 + (j&127)*2  (128 slots per row)
__device__ __forceinline__ unsigned short* hslot2(char* o, long j) {
  return (unsigned short*)(o + (j >> 7) * 512 + (j & 127) * 2);
}
__device__ __forceinline__ void store8u16(char* o, long s, uint4 v) {
  *(uint4*)(o + (s >> 7) * 512 + (s & 127) * 2) = v;  // s % 8 == 0
}
// h-region slots: deg copies [0, 3.2M) ; cnt copies [3.2M, 6.4M)
// c-region slots: segbase [0, 3.2M) ; rank [3.2M, 4.0M)
#define CNT_SLOT0 3200000L
#define RANK_SLOT0 3200000L

// ---------------- phase 1: LDS histograms + buildB + h->bf16 + x->bf16 ----------------
__global__ __launch_bounds__(1024) void k_pre(
    const float* __restrict__ Wi, const float* __restrict__ Wf,
    const float* __restrict__ Wc, const float* __restrict__ Wo,
    const float* __restrict__ Ti, const float* __restrict__ Tf,
    const float* __restrict__ Tc, const float* __restrict__ To,
    unsigned short* __restrict__ bglob, const float* __restrict__ h,
    const float* __restrict__ x, char* __restrict__ outB,
    const int* __restrict__ src, const int* __restrict__ dst,
    const float* __restrict__ w) {
  __shared__ unsigned hist[25000];  // 100 KB: packed 2 x u16 bins, all 50000 nodes
  const int b = blockIdx.x, tid = threadIdx.x;
  char* cB = outB + (long)NN * 512;
  if (b < KC) {
    uint4* h4 = (uint4*)hist;
    const int base = b * EPC;
    // ---- pass A: cnt (packed u16) + rank ----
    for (int j = tid; j < 6250; j += 1024) h4[j] = (uint4){0u, 0u, 0u, 0u};
    __syncthreads();
    for (int k = tid; k < EPC; k += 1024) {
      const int e = base + k;
      const int d = dst[e];
      const int sh = (d & 1) * 16;
      const unsigned old = atomicAdd(&hist[d >> 1], 1u << sh);
      *hslot2(cB, RANK_SLOT0 + e) = (unsigned short)((old >> sh) & 0xffffu);
    }
    __syncthreads();
    for (int j = tid; j < 6250; j += 1024)
      store8u16(outB, CNT_SLOT0 + (long)b * NN + j * 8, h4[j]);
    __syncthreads();
    // ---- pass B: deg (packed u16 fixed-point, scale 2^12) ----
    for (int j = tid; j < 6250; j += 1024) h4[j] = (uint4){0u, 0u, 0u, 0u};
    __syncthreads();
    for (int k = tid; k < EPC; k += 1024) {
      const int e = base + k;
      const int s = src[e];
      const unsigned q = (unsigned)__float2uint_rn(w[e] * DEG_SCALE);
      const int sh = (s & 1) * 16;
      atomicAdd(&hist[s >> 1], q << sh);
    }
    __syncthreads();
    for (int j = tid; j < 6250; j += 1024)
      store8u16(outB, (long)b * NN + j * 8, h4[j]);
  } else if (b < KC + 32) {
    // buildB: fragment-native
    const int t = (b - KC) * 1024 + tid;  // 0..32767
    const int ks = t >> 11;
    const int cf = (t >> 6) & 31;
    const int lane = t & 63;
    const int wv = cf >> 3, hl = (cf >> 2) & 1, g = cf & 3;
    const int kg = lane >> 4, lm = lane & 15;
    const int hc = (wv * 2 + hl) * 16 + lm;
    const float* Wg = (g == 0) ? Wi : (g == 1) ? Wf : (g == 2) ? Wc : Wo;
    const float* Tg = (g == 0) ? Ti : (g == 1) ? Tf : (g == 2) ? Tc : To;
    u16x8 out;
#pragma unroll
    for (int dk = 0; dk < 8; ++dk) {
      const int k = ks * 32 + kg * 8 + dk;
      const int kb = k >> 7, r = k & 127;
      const float v = (kb == 0) ? Wg[r * 128 + hc] : Tg[(kb - 1) * 16384 + r * 128 + hc];
      out[dk] = f2bf(v);
    }
    *(u16x8*)(bglob + t * 8) = out;
  } else if (b < KC + 32 + 782) {
    const int i = (b - (KC + 32)) * 1024 + tid;  // 8-f32 chunks of h
    if (i < 100000 * 8) {
      const float* hp = h + i * 8;
      const f32x4 v0 = *(const f32x4*)hp;
      const f32x4 v1 = *(const f32x4*)(hp + 4);
      u16x8 o;
#pragma unroll
      for (int e = 0; e < 4; ++e) o[e] = f2bf(v0[e]);
#pragma unroll
      for (int e = 0; e < 4; ++e) o[e + 4] = f2bf(v1[e]);
      *(u16x8*)(outB + (i >> 4) * 512 + 256 + (i & 15) * 16) = o;
    }
  } else {
    const int i = (b - (KC + 32 + 782)) * 1024 + tid;
    if (i < 100000 * 8) {
      const float* xp = x + i * 8;
      const f32x4 v0 = *(const f32x4*)xp;
      const f32x4 v1 = *(const f32x4*)(xp + 4);
      u16x8 o;
#pragma unroll
      for (int e = 0; e < 4; ++e) o[e] = f2bf(v0[e]);
#pragma unroll
      for (int e = 0; e < 4; ++e) o[e + 4] = f2bf(v1[e]);
      *(u16x8*)(cB + (i >> 4) * 512 + 256 + (i & 15) * 16) = o;
    }
  }
}

// ---------------- scan machinery ----------------
__device__ __forceinline__ int block_scan_excl_256(int v, int* total) {
  __shared__ int wsum[4];
  const int tid = threadIdx.x;
  const int lane = tid & 63, wv = tid >> 6;
  int x = v;
#pragma unroll
  for (int d = 1; d < 64; d <<= 1) {
    const int y = __shfl_up(x, d, 64);
    if (lane >= d) x += y;
  }
  if (lane == 63) wsum[wv] = x;
  __syncthreads();
  int pre = 0, tot = 0;
#pragma unroll
  for (int u = 0; u < 4; ++u) {
    const int s = wsum[u];
    pre += (u < wv) ? s : 0;
    tot += s;
  }
  *total = tot;
  return pre + x - v;
}

// reduce deg copies -> dinv; running-sum cnt copies -> segbase (c-region) + wscnt
__global__ void k_phase2(char* __restrict__ outB, float* __restrict__ dinv,
                         int* __restrict__ wscnt, int* __restrict__ bsum) {
  char* cB = outB + (long)NN * 512;
  const int i = blockIdx.x * 256 + threadIdx.x;
  int run = 0;
  if (i < NN) {
    float s = 0.f;
#pragma unroll
    for (int c = 0; c < KC; ++c)
      s += (float)*hslot2(outB, (long)c * NN + i);
    s *= (1.0f / DEG_SCALE);
    dinv[i] = (s > 0.f) ? rsqrtf(fmaxf(s, 1e-30f)) : 0.f;
#pragma unroll
    for (int c = 0; c < KC; ++c) {
      *hslot2(cB, (long)c * NN + i) = (unsigned short)run;
      run += (int)*hslot2(outB, CNT_SLOT0 + (long)c * NN + i);
    }
    wscnt[i] = run;
  }
  int tot;
  block_scan_excl_256(run, &tot);
  if (threadIdx.x == 0) bsum[blockIdx.x] = tot;
}

__global__ void k_scan2(const int* __restrict__ bsum, int* __restrict__ boff,
                        const int nb) {
  const int t = threadIdx.x;
  const int v = (t < nb) ? bsum[t] : 0;
  int tot;
  const int excl = block_scan_excl_256(v, &tot);
  if (t <= nb) boff[t] = excl;
}

__global__ void k_scan3(const int* __restrict__ cnt, const int* __restrict__ boff,
                        int* __restrict__ off) {
  const int i = blockIdx.x * 256 + threadIdx.x;
  const int v = (i < NN) ? cnt[i] : 0;
  int tot;
  const int excl = block_scan_excl_256(v, &tot) + boff[blockIdx.x];
  if (i < NN) off[i] = excl;
  if (i == NN) off[NN] = excl;
}

// atomic-free CSR fill: p = off[d] + segbase[copy][d] + rank[e]
__global__ void k_edge2(const int* __restrict__ src, const int* __restrict__ dst,
                        const float* __restrict__ w, const float* __restrict__ dinv,
                        const int* __restrict__ off, char* __restrict__ outB,
                        int2* __restrict__ ed) {
  const int e = blockIdx.x * blockDim.x + threadIdx.x;
  if (e >= EE) return;
  char* cB = outB + (long)NN * 512;
  const int s = src[e], d = dst[e];
  const int c = e / EPC;
  const int p = off[d] + (int)*hslot2(cB, (long)c * NN + d) +
                (int)*hslot2(cB, RANK_SLOT0 + e);
  int2 rec;
  rec.x = s;
  rec.y = __float_as_int(-w[e] * dinv[s] * dinv[d]);
  ed[p] = rec;
}

// ---------------- sparse gather (bf16 rows, 1 wave per node) ----------------
__global__ __launch_bounds__(256) void k_gather(
    const char* __restrict__ vinB, const char* __restrict__ vsubB, const float alpha,
    const int* __restrict__ off, const int2* __restrict__ ed, char* __restrict__ voutB) {
  const int wid = threadIdx.x >> 6, lane = threadIdx.x & 63;
  const int node = blockIdx.x * 4 + wid;
  const int p0 = off[node], p1 = off[node + 1];
  const int lb = lane * 4;
  float ax0 = 0.f, ay0 = 0.f, ax1 = 0.f, ay1 = 0.f;
  float ax2 = 0.f, ay2 = 0.f, ax3 = 0.f, ay3 = 0.f;
  int p = p0;
  for (; p + 7 < p1; p += 8) {
    int2 E[8];
    unsigned V[8];
#pragma unroll
    for (int u = 0; u < 8; ++u) E[u] = ed[p + u];
#pragma unroll
    for (int u = 0; u < 8; ++u)
      V[u] = *(const unsigned*)(vinB + (long)E[u].x * 512 + lb);
#pragma unroll
    for (int u = 0; u < 8; ++u) {
      const float wv = __int_as_float(E[u].y);
      float* ax = (u & 3) == 0 ? &ax0 : (u & 3) == 1 ? &ax1 : (u & 3) == 2 ? &ax2 : &ax3;
      float* ay = (u & 3) == 0 ? &ay0 : (u & 3) == 1 ? &ay1 : (u & 3) == 2 ? &ay2 : &ay3;
      *ax = fmaf(wv, bf2f((unsigned short)V[u]), *ax);
      *ay = fmaf(wv, bf2f((unsigned short)(V[u] >> 16)), *ay);
    }
  }
  for (; p + 3 < p1; p += 4) {
    const int2 e0 = ed[p], e1 = ed[p + 1], e2 = ed[p + 2], e3 = ed[p + 3];
    const unsigned v0 = *(const unsigned*)(vinB + (long)e0.x * 512 + lb);
    const unsigned v1 = *(const unsigned*)(vinB + (long)e1.x * 512 + lb);
    const unsigned v2 = *(const unsigned*)(vinB + (long)e2.x * 512 + lb);
    const unsigned v3 = *(const unsigned*)(vinB + (long)e3.x * 512 + lb);
    const float w0 = __int_as_float(e0.y), w1 = __int_as_float(e1.y);
    const float w2 = __int_as_float(e2.y), w3 = __int_as_float(e3.y);
    ax0 = fmaf(w0, bf2f((unsigned short)v0), ax0);
    ay0 = fmaf(w0, bf2f((unsigned short)(v0 >> 16)), ay0);
    ax1 = fmaf(w1, bf2f((unsigned short)v1), ax1);
    ay1 = fmaf(w1, bf2f((unsigned short)(v1 >> 16)), ay1);
    ax2 = fmaf(w2, bf2f((unsigned short)v2), ax2);
    ay2 = fmaf(w2, bf2f((unsigned short)(v2 >> 16)), ay2);
    ax3 = fmaf(w3, bf2f((unsigned short)v3), ax3);
    ay3 = fmaf(w3, bf2f((unsigned short)(v3 >> 16)), ay3);
  }
  for (; p < p1; ++p) {
    const int2 e0 = ed[p];
    const unsigned v0 = *(const unsigned*)(vinB + (long)e0.x * 512 + lb);
    const float w0 = __int_as_float(e0.y);
    ax0 = fmaf(w0, bf2f((unsigned short)v0), ax0);
    ay0 = fmaf(w0, bf2f((unsigned short)(v0 >> 16)), ay0);
  }
  float rx = alpha * ((ax0 + ax1) + (ax2 + ax3));
  float ry = alpha * ((ay0 + ay1) + (ay2 + ay3));
  if (vsubB) {
    const unsigned s = *(const unsigned*)(vsubB + (long)node * 512 + lb);
    rx -= bf2f((unsigned short)s);
    ry -= bf2f((unsigned short)(s >> 16));
  }
  const unsigned ow = (unsigned)f2bf(rx) | ((unsigned)f2bf(ry) << 16);
  *(unsigned*)(voutB + (long)node * 512 + lb) = ow;
}

// ---------------- dense stage (as rounds 4-6) ----------------
__global__ __launch_bounds__(256, 2) void k_gemm(
    const char* __restrict__ outB, const unsigned short* __restrict__ bglob,
    const float* __restrict__ c_prev,
    const float* __restrict__ b_i, const float* __restrict__ b_f,
    const float* __restrict__ b_c, const float* __restrict__ b_o,
    const float* __restrict__ w_ci, const float* __restrict__ w_cf,
    const float* __restrict__ w_co, float* __restrict__ h_out,
    float* __restrict__ c_out) {
  __shared__ char lds[2][4096];
  const int tid = threadIdx.x;
  const int lane = tid & 63;
  const int wid = tid >> 6;
  const int kg = lane >> 4;
  const int lm = lane & 15;
  const int m0 = blockIdx.x * 64;

  const char* hB = outB;                   // +0: tx1b, +256: hb
  const char* cB = outB + (long)NN * 512;  // +0: tx2b, +256: xb

  const int srow0 = m0 + wid * 16 + lm;
  const long srow = (srow0 < NN) ? srow0 : (NN - 1);
  const int schunk = kg * 16;

  f32x4 acc[32];
#pragma unroll
  for (int i = 0; i < 32; ++i) acc[i] = (f32x4){0.f, 0.f, 0.f, 0.f};

  auto stage = [&](int ks, int buf) {
    const char* base = (ks < 4) ? (cB + 256) : (ks < 8) ? (hB + 256) : (ks < 12) ? hB : cB;
    async_copy16(base + srow * 512 + (ks & 3) * 64 + schunk, &lds[buf][tid * 16]);
  };

  bf16x8 br0[8], br1[8];
  auto loadB = [&](int ks, bf16x8* bb) {
    const unsigned short* fp = bglob + ((ks * 32 + wid * 8) * 64 + lane) * 8;
#pragma unroll
    for (int i = 0; i < 8; ++i) bb[i] = *(const bf16x8*)(fp + i * 512);
  };

  stage(0, 0);
  loadB(0, br0);
  __syncthreads();

#pragma unroll
  for (int ks = 0; ks < 16; ++ks) {
    const int buf = ks & 1;
    if (ks < 15) {
      stage(ks + 1, buf ^ 1);
      loadB(ks + 1, (ks & 1) ? br0 : br1);
    }
    bf16x8 a[4];
#pragma unroll
    for (int rf = 0; rf < 4; ++rf)
      a[rf] = *(const bf16x8*)(&lds[buf][rf * 1024 + lane * 16]);
    const bf16x8* br = (ks & 1) ? br1 : br0;
#pragma unroll
    for (int rf = 0; rf < 4; ++rf)
#pragma unroll
      for (int i = 0; i < 8; ++i)
        acc[rf * 8 + i] =
            __builtin_amdgcn_mfma_f32_16x16x32_bf16(a[rf], br[i], acc[rf * 8 + i], 0, 0, 0);
    __syncthreads();
  }

#pragma unroll
  for (int hl = 0; hl < 2; ++hl) {
    const int hc = (wid * 2 + hl) * 16 + lm;
    const float bi = b_i[hc], bfv = b_f[hc], bc = b_c[hc], bo = b_o[hc];
    const float wci = w_ci[hc], wcf = w_cf[hc], wco = w_co[hc];
#pragma unroll
    for (int rf = 0; rf < 4; ++rf) {
#pragma unroll
      for (int reg = 0; reg < 4; ++reg) {
        const int node = m0 + rf * 16 + kg * 4 + reg;
        if (node < NN) {
          const float cp = c_prev[node * 128 + hc];
          const float pi = acc[rf * 8 + hl * 4 + 0][reg] + bi + wci * cp;
          const float pf = acc[rf * 8 + hl * 4 + 1][reg] + bfv + wcf * cp;
          const float pc = acc[rf * 8 + hl * 4 + 2][reg] + bc;
          const float po = acc[rf * 8 + hl * 4 + 3][reg] + bo;
          const float ig = 1.f / (1.f + __expf(-pi));
          const float fg = 1.f / (1.f + __expf(-pf));
          const float ct = fg * cp + ig * tanhf(pc);
          const float og = 1.f / (1.f + __expf(-(po + wco * ct)));
          h_out[node * 128 + hc] = og * tanhf(ct);
          c_out[node * 128 + hc] = ct;
        }
      }
    }
  }
}

// ---------------- launcher ----------------

extern "C" void kernel_launch(void* const* d_in, const int* in_sizes, int n_in,
                              void* d_out, int out_size, void* d_ws, size_t ws_size,
                              hipStream_t stream) {
  const float* x_t    = (const float*)d_in[0];
  const float* h_prev = (const float*)d_in[1];
  const float* c_prev = (const float*)d_in[2];
  const float* ew     = (const float*)d_in[3];
  const int*   eidx   = (const int*)d_in[4];
  const float* Wi = (const float*)d_in[5];
  const float* Wf = (const float*)d_in[6];
  const float* Wc = (const float*)d_in[7];
  const float* Wo = (const float*)d_in[8];
  const float* Ti = (const float*)d_in[9];
  const float* Tf = (const float*)d_in[10];
  const float* Tc = (const float*)d_in[11];
  const float* To = (const float*)d_in[12];
  const float* bi = (const float*)d_in[13];
  const float* bf = (const float*)d_in[14];
  const float* bc = (const float*)d_in[15];
  const float* bo = (const float*)d_in[16];
  const float* wci = (const float*)d_in[17];
  const float* wcf = (const float*)d_in[18];
  const float* wco = (const float*)d_in[19];

  char* ws = (char*)d_ws;
  float* dinv  = (float*)(ws + 0);        // 200192
  int*   wscnt = (int*)(ws + 200192);     // 200192
  int*   off   = (int*)(ws + 400384);     // 200704
  int*   bsum  = (int*)(ws + 601088);     // 1024
  int*   boff  = (int*)(ws + 602112);     // 1024
  int2*  ed    = (int2*)(ws + 603136);    // 6400000
  unsigned short* bglob = (unsigned short*)(ws + 7003136);  // 524288

  char* outB = (char*)d_out;  // h-rows: [deg/cnt -> tx1b | hb]; c-rows: [segbase/rank -> tx2b | xb]
  float* h_out = (float*)d_out;
  float* c_out = h_out + (long)NN * 128;

  const int* esrc = eidx;
  const int* edst = eidx + EE;

  k_pre<<<KC + 32 + 782 + 782, 1024, 0, stream>>>(
      Wi, Wf, Wc, Wo, Ti, Tf, Tc, To, bglob, h_prev, x_t, outB, esrc, edst, ew);
  k_phase2<<<196, 256, 0, stream>>>(outB, dinv, wscnt, bsum);
  k_scan2<<<1, 256, 0, stream>>>(bsum, boff, 196);
  k_scan3<<<196, 256, 0, stream>>>(wscnt, boff, off);
  k_edge2<<<3125, 256, 0, stream>>>(esrc, edst, ew, dinv, off, outB, ed);
  k_gather<<<12500, 256, 0, stream>>>(outB + 256, nullptr, 1.f, off, ed, outB);
  k_gather<<<12500, 256, 0, stream>>>(outB, outB + 256, 2.f, off, ed,
                                      outB + (long)NN * 512);
  k_gemm<<<782, 256, 0, stream>>>(outB, bglob, c_prev,
                                  bi, bf, bc, bo, wci, wcf, wco, h_out, c_out);
}

// Round 8
// 225.843 us; speedup vs baseline: 1.5950x; 1.0036x over previous
//
#include <hip/hip_runtime.h>

#define NN 50000
#define EE 800000
#define KC 64          // histogram copies (one hist block each)
#define EPC (EE / KC)  // 12500 edges per hist block
#define DEG_SCALE 4096.0f

typedef float f32x4 __attribute__((ext_vector_type(4)));
typedef short bf16x8 __attribute__((ext_vector_type(8)));
typedef unsigned short u16x8 __attribute__((ext_vector_type(8)));

__device__ __forceinline__ unsigned short f2bf(float f) {
  unsigned int u = __float_as_uint(f);
  u += 0x7fffu + ((u >> 16) & 1u);
  return (unsigned short)(u >> 16);
}
__device__ __forceinline__ float bf2f(unsigned short u) {
  return __uint_as_float(((unsigned int)u) << 16);
}

__device__ __forceinline__ void async_copy16(const void* g, void* l) {
  __builtin_amdgcn_global_load_lds(
      (const __attribute__((address_space(1))) unsigned int*)g,
      (__attribute__((address_space(3))) unsigned int*)l, 16, 0, 0);
}

// ---- u16-slot scratch in the first 256B of each 512B d_out row ----
__device__ __forceinline__ unsigned short* hslot2(char* o, long j) {
  return (unsigned short*)(o + (j >> 7) * 512 + (j & 127) * 2);
}
__device__ __forceinline__ void store8u16(char* o, long s, uint4 v) {
  *(uint4*)(o + (s >> 7) * 512 + (s & 127) * 2) = v;  // s % 8 == 0
}
// h-region slots: deg copies [0, 3.2M) ; cnt copies [3.2M, 6.4M)
// c-region slots: segbase [0, 3.2M) ; rank [3.2M, 4.0M)
#define CNT_SLOT0 3200000L
#define RANK_SLOT0 3200000L

// ---------------- phase 1: LDS histograms + buildB + h->bf16 + x->bf16 ----------------
__global__ __launch_bounds__(1024) void k_pre(
    const float* __restrict__ Wi, const float* __restrict__ Wf,
    const float* __restrict__ Wc, const float* __restrict__ Wo,
    const float* __restrict__ Ti, const float* __restrict__ Tf,
    const float* __restrict__ Tc, const float* __restrict__ To,
    unsigned short* __restrict__ bglob, const float* __restrict__ h,
    const float* __restrict__ x, char* __restrict__ outB,
    const int* __restrict__ src, const int* __restrict__ dst,
    const float* __restrict__ w) {
  __shared__ unsigned hist[25000];  // 100 KB: packed 2 x u16 bins, all 50000 nodes
  const int b = blockIdx.x, tid = threadIdx.x;
  char* cB = outB + (long)NN * 512;
  if (b < KC) {
    uint4* h4 = (uint4*)hist;
    const int base = b * EPC;
    // ---- pass A: cnt (packed u16) + rank ----
    for (int j = tid; j < 6250; j += 1024) h4[j] = (uint4){0u, 0u, 0u, 0u};
    __syncthreads();
    for (int k = tid; k < EPC; k += 1024) {
      const int e = base + k;
      const int d = dst[e];
      const int sh = (d & 1) * 16;
      const unsigned old = atomicAdd(&hist[d >> 1], 1u << sh);
      *hslot2(cB, RANK_SLOT0 + e) = (unsigned short)((old >> sh) & 0xffffu);
    }
    __syncthreads();
    for (int j = tid; j < 6250; j += 1024)
      store8u16(outB, CNT_SLOT0 + (long)b * NN + j * 8, h4[j]);
    __syncthreads();
    // ---- pass B: deg (packed u16 fixed-point, scale 2^12) ----
    for (int j = tid; j < 6250; j += 1024) h4[j] = (uint4){0u, 0u, 0u, 0u};
    __syncthreads();
    for (int k = tid; k < EPC; k += 1024) {
      const int e = base + k;
      const int s = src[e];
      const unsigned q = (unsigned)__float2uint_rn(w[e] * DEG_SCALE);
      const int sh = (s & 1) * 16;
      atomicAdd(&hist[s >> 1], q << sh);
    }
    __syncthreads();
    for (int j = tid; j < 6250; j += 1024)
      store8u16(outB, (long)b * NN + j * 8, h4[j]);
  } else if (b < KC + 32) {
    // buildB: fragment-native
    const int t = (b - KC) * 1024 + tid;  // 0..32767
    const int ks = t >> 11;
    const int cf = (t >> 6) & 31;
    const int lane = t & 63;
    const int wv = cf >> 3, hl = (cf >> 2) & 1, g = cf & 3;
    const int kg = lane >> 4, lm = lane & 15;
    const int hc = (wv * 2 + hl) * 16 + lm;
    const float* Wg = (g == 0) ? Wi : (g == 1) ? Wf : (g == 2) ? Wc : Wo;
    const float* Tg = (g == 0) ? Ti : (g == 1) ? Tf : (g == 2) ? Tc : To;
    u16x8 out;
#pragma unroll
    for (int dk = 0; dk < 8; ++dk) {
      const int k = ks * 32 + kg * 8 + dk;
      const int kb = k >> 7, r = k & 127;
      const float v = (kb == 0) ? Wg[r * 128 + hc] : Tg[(kb - 1) * 16384 + r * 128 + hc];
      out[dk] = f2bf(v);
    }
    *(u16x8*)(bglob + t * 8) = out;
  } else if (b < KC + 32 + 782) {
    const int i = (b - (KC + 32)) * 1024 + tid;  // 8-f32 chunks of h
    if (i < 100000 * 8) {
      const float* hp = h + i * 8;
      const f32x4 v0 = *(const f32x4*)hp;
      const f32x4 v1 = *(const f32x4*)(hp + 4);
      u16x8 o;
#pragma unroll
      for (int e = 0; e < 4; ++e) o[e] = f2bf(v0[e]);
#pragma unroll
      for (int e = 0; e < 4; ++e) o[e + 4] = f2bf(v1[e]);
      *(u16x8*)(outB + (i >> 4) * 512 + 256 + (i & 15) * 16) = o;
    }
  } else {
    const int i = (b - (KC + 32 + 782)) * 1024 + tid;
    if (i < 100000 * 8) {
      const float* xp = x + i * 8;
      const f32x4 v0 = *(const f32x4*)xp;
      const f32x4 v1 = *(const f32x4*)(xp + 4);
      u16x8 o;
#pragma unroll
      for (int e = 0; e < 4; ++e) o[e] = f2bf(v0[e]);
#pragma unroll
      for (int e = 0; e < 4; ++e) o[e + 4] = f2bf(v1[e]);
      *(u16x8*)(cB + (i >> 4) * 512 + 256 + (i & 15) * 16) = o;
    }
  }
}

// ---------------- scan machinery ----------------
__device__ __forceinline__ int block_scan_excl_256(int v, int* total) {
  __shared__ int wsum[4];
  const int tid = threadIdx.x;
  const int lane = tid & 63, wv = tid >> 6;
  int x = v;
#pragma unroll
  for (int d = 1; d < 64; d <<= 1) {
    const int y = __shfl_up(x, d, 64);
    if (lane >= d) x += y;
  }
  if (lane == 63) wsum[wv] = x;
  __syncthreads();
  int pre = 0, tot = 0;
#pragma unroll
  for (int u = 0; u < 4; ++u) {
    const int s = wsum[u];
    pre += (u < wv) ? s : 0;
    tot += s;
  }
  *total = tot;
  return pre + x - v;
}

// reduce deg copies -> dinv; running-sum cnt copies -> segbase (c-region) + wscnt
__global__ void k_phase2(char* __restrict__ outB, float* __restrict__ dinv,
                         int* __restrict__ wscnt, int* __restrict__ bsum) {
  char* cB = outB + (long)NN * 512;
  const int i = blockIdx.x * 256 + threadIdx.x;
  int run = 0;
  if (i < NN) {
    float s = 0.f;
#pragma unroll
    for (int c = 0; c < KC; ++c)
      s += (float)*hslot2(outB, (long)c * NN + i);
    s *= (1.0f / DEG_SCALE);
    dinv[i] = (s > 0.f) ? rsqrtf(fmaxf(s, 1e-30f)) : 0.f;
#pragma unroll
    for (int c = 0; c < KC; ++c) {
      *hslot2(cB, (long)c * NN + i) = (unsigned short)run;
      run += (int)*hslot2(outB, CNT_SLOT0 + (long)c * NN + i);
    }
    wscnt[i] = run;
  }
  int tot;
  block_scan_excl_256(run, &tot);
  if (threadIdx.x == 0) bsum[blockIdx.x] = tot;
}

__global__ void k_scan2(const int* __restrict__ bsum, int* __restrict__ boff,
                        const int nb) {
  const int t = threadIdx.x;
  const int v = (t < nb) ? bsum[t] : 0;
  int tot;
  const int excl = block_scan_excl_256(v, &tot);
  if (t <= nb) boff[t] = excl;
}

__global__ void k_scan3(const int* __restrict__ cnt, const int* __restrict__ boff,
                        int* __restrict__ off) {
  const int i = blockIdx.x * 256 + threadIdx.x;
  const int v = (i < NN) ? cnt[i] : 0;
  int tot;
  const int excl = block_scan_excl_256(v, &tot) + boff[blockIdx.x];
  if (i < NN) off[i] = excl;
  if (i == NN) off[NN] = excl;
}

// atomic-free CSR fill: p = off[d] + segbase[copy][d] + rank[e]
__global__ void k_edge2(const int* __restrict__ src, const int* __restrict__ dst,
                        const float* __restrict__ w, const float* __restrict__ dinv,
                        const int* __restrict__ off, char* __restrict__ outB,
                        int2* __restrict__ ed) {
  const int e = blockIdx.x * blockDim.x + threadIdx.x;
  if (e >= EE) return;
  char* cB = outB + (long)NN * 512;
  const int s = src[e], d = dst[e];
  const int c = e / EPC;
  const int p = off[d] + (int)*hslot2(cB, (long)c * NN + d) +
                (int)*hslot2(cB, RANK_SLOT0 + e);
  int2 rec;
  rec.x = s;
  rec.y = __float_as_int(-w[e] * dinv[s] * dinv[d]);
  ed[p] = rec;
}

// ---------------- sparse gather (bf16 rows, 1 wave per node) ----------------
__global__ __launch_bounds__(256) void k_gather(
    const char* __restrict__ vinB, const char* __restrict__ vsubB, const float alpha,
    const int* __restrict__ off, const int2* __restrict__ ed, char* __restrict__ voutB) {
  const int wid = threadIdx.x >> 6, lane = threadIdx.x & 63;
  const int node = blockIdx.x * 4 + wid;
  const int p0 = off[node], p1 = off[node + 1];
  const int lb = lane * 4;
  float ax0 = 0.f, ay0 = 0.f, ax1 = 0.f, ay1 = 0.f;
  float ax2 = 0.f, ay2 = 0.f, ax3 = 0.f, ay3 = 0.f;
  int p = p0;
  for (; p + 7 < p1; p += 8) {
    int2 E[8];
    unsigned V[8];
#pragma unroll
    for (int u = 0; u < 8; ++u) E[u] = ed[p + u];
#pragma unroll
    for (int u = 0; u < 8; ++u)
      V[u] = *(const unsigned*)(vinB + (long)E[u].x * 512 + lb);
#pragma unroll
    for (int u = 0; u < 8; ++u) {
      const float wv = __int_as_float(E[u].y);
      float* ax = (u & 3) == 0 ? &ax0 : (u & 3) == 1 ? &ax1 : (u & 3) == 2 ? &ax2 : &ax3;
      float* ay = (u & 3) == 0 ? &ay0 : (u & 3) == 1 ? &ay1 : (u & 3) == 2 ? &ay2 : &ay3;
      *ax = fmaf(wv, bf2f((unsigned short)V[u]), *ax);
      *ay = fmaf(wv, bf2f((unsigned short)(V[u] >> 16)), *ay);
    }
  }
  for (; p + 3 < p1; p += 4) {
    const int2 e0 = ed[p], e1 = ed[p + 1], e2 = ed[p + 2], e3 = ed[p + 3];
    const unsigned v0 = *(const unsigned*)(vinB + (long)e0.x * 512 + lb);
    const unsigned v1 = *(const unsigned*)(vinB + (long)e1.x * 512 + lb);
    const unsigned v2 = *(const unsigned*)(vinB + (long)e2.x * 512 + lb);
    const unsigned v3 = *(const unsigned*)(vinB + (long)e3.x * 512 + lb);
    const float w0 = __int_as_float(e0.y), w1 = __int_as_float(e1.y);
    const float w2 = __int_as_float(e2.y), w3 = __int_as_float(e3.y);
    ax0 = fmaf(w0, bf2f((unsigned short)v0), ax0);
    ay0 = fmaf(w0, bf2f((unsigned short)(v0 >> 16)), ay0);
    ax1 = fmaf(w1, bf2f((unsigned short)v1), ax1);
    ay1 = fmaf(w1, bf2f((unsigned short)(v1 >> 16)), ay1);
    ax2 = fmaf(w2, bf2f((unsigned short)v2), ax2);
    ay2 = fmaf(w2, bf2f((unsigned short)(v2 >> 16)), ay2);
    ax3 = fmaf(w3, bf2f((unsigned short)v3), ax3);
    ay3 = fmaf(w3, bf2f((unsigned short)(v3 >> 16)), ay3);
  }
  for (; p < p1; ++p) {
    const int2 e0 = ed[p];
    const unsigned v0 = *(const unsigned*)(vinB + (long)e0.x * 512 + lb);
    const float w0 = __int_as_float(e0.y);
    ax0 = fmaf(w0, bf2f((unsigned short)v0), ax0);
    ay0 = fmaf(w0, bf2f((unsigned short)(v0 >> 16)), ay0);
  }
  float rx = alpha * ((ax0 + ax1) + (ax2 + ax3));
  float ry = alpha * ((ay0 + ay1) + (ay2 + ay3));
  if (vsubB) {
    const unsigned s = *(const unsigned*)(vsubB + (long)node * 512 + lb);
    rx -= bf2f((unsigned short)s);
    ry -= bf2f((unsigned short)(s >> 16));
  }
  const unsigned ow = (unsigned)f2bf(rx) | ((unsigned)f2bf(ry) << 16);
  *(unsigned*)(voutB + (long)node * 512 + lb) = ow;
}

// ---------------- dense stage: upfront A-panel stage, barrier-free K-loop ----------------
// A = [xb | hb | tx1b | tx2b] (64 rows x 512 bf16) staged ONCE into 64KB LDS as
// MFMA fragments; single __syncthreads; then 16 k-steps of {4 ds_read_b128,
// 8 B-frag L2 loads (ping-pong regs), 32 MFMA} with NO barriers -> B prefetch
// stays in flight across steps (counted vmcnt only, compiler-managed).
__global__ __launch_bounds__(256, 2) void k_gemm(
    const char* __restrict__ outB, const unsigned short* __restrict__ bglob,
    const float* __restrict__ c_prev,
    const float* __restrict__ b_i, const float* __restrict__ b_f,
    const float* __restrict__ b_c, const float* __restrict__ b_o,
    const float* __restrict__ w_ci, const float* __restrict__ w_cf,
    const float* __restrict__ w_co, float* __restrict__ h_out,
    float* __restrict__ c_out) {
  __shared__ char lds[65536];
  const int tid = threadIdx.x;
  const int lane = tid & 63;
  const int wid = tid >> 6;
  const int kg = lane >> 4;
  const int lm = lane & 15;
  const int m0 = blockIdx.x * 64;

  const char* hB = outB;                   // +0: tx1b, +256: hb
  const char* cB = outB + (long)NN * 512;  // +0: tx2b, +256: xb

  const int srow0 = m0 + wid * 16 + lm;
  const long srow = (srow0 < NN) ? srow0 : (NN - 1);
  const int schunk = kg * 16;

  // prologue: stage the whole A panel (16 k-tiles x 4KB)
#pragma unroll
  for (int ks = 0; ks < 16; ++ks) {
    const char* base = (ks < 4) ? (cB + 256) : (ks < 8) ? (hB + 256) : (ks < 12) ? hB : cB;
    async_copy16(base + srow * 512 + (ks & 3) * 64 + schunk,
                 &lds[ks * 4096 + tid * 16]);
  }

  f32x4 acc[32];
#pragma unroll
  for (int i = 0; i < 32; ++i) acc[i] = (f32x4){0.f, 0.f, 0.f, 0.f};

  bf16x8 b0[8], b1[8];
  auto loadB = [&](int ks, bf16x8* bb) {
    const unsigned short* fp = bglob + ((ks * 32 + wid * 8) * 64 + lane) * 8;
#pragma unroll
    for (int i = 0; i < 8; ++i) bb[i] = *(const bf16x8*)(fp + i * 512);
  };

  __syncthreads();  // single full drain: A panel resident in LDS after this

  loadB(0, b0);
#pragma unroll
  for (int ks = 0; ks < 16; ++ks) {
    bf16x8* bc = (ks & 1) ? b1 : b0;
    bf16x8* bn = (ks & 1) ? b0 : b1;
    if (ks < 15) loadB(ks + 1, bn);
    bf16x8 a[4];
#pragma unroll
    for (int rf = 0; rf < 4; ++rf)
      a[rf] = *(const bf16x8*)(&lds[ks * 4096 + rf * 1024 + lane * 16]);
#pragma unroll
    for (int rf = 0; rf < 4; ++rf)
#pragma unroll
      for (int i = 0; i < 8; ++i)
        acc[rf * 8 + i] =
            __builtin_amdgcn_mfma_f32_16x16x32_bf16(a[rf], bc[i], acc[rf * 8 + i], 0, 0, 0);
  }

  // Epilogue (block owns rows m0..m0+63 exclusively; all global A reads were
  // drained at the prologue barrier, so overwriting d_out rows here is safe)
#pragma unroll
  for (int hl = 0; hl < 2; ++hl) {
    const int hc = (wid * 2 + hl) * 16 + lm;
    const float bi = b_i[hc], bfv = b_f[hc], bc = b_c[hc], bo = b_o[hc];
    const float wci = w_ci[hc], wcf = w_cf[hc], wco = w_co[hc];
#pragma unroll
    for (int rf = 0; rf < 4; ++rf) {
#pragma unroll
      for (int reg = 0; reg < 4; ++reg) {
        const int node = m0 + rf * 16 + kg * 4 + reg;
        if (node < NN) {
          const float cp = c_prev[node * 128 + hc];
          const float pi = acc[rf * 8 + hl * 4 + 0][reg] + bi + wci * cp;
          const float pf = acc[rf * 8 + hl * 4 + 1][reg] + bfv + wcf * cp;
          const float pc = acc[rf * 8 + hl * 4 + 2][reg] + bc;
          const float po = acc[rf * 8 + hl * 4 + 3][reg] + bo;
          const float ig = 1.f / (1.f + __expf(-pi));
          const float fg = 1.f / (1.f + __expf(-pf));
          const float ct = fg * cp + ig * tanhf(pc);
          const float og = 1.f / (1.f + __expf(-(po + wco * ct)));
          h_out[node * 128 + hc] = og * tanhf(ct);
          c_out[node * 128 + hc] = ct;
        }
      }
    }
  }
}

// ---------------- launcher ----------------

extern "C" void kernel_launch(void* const* d_in, const int* in_sizes, int n_in,
                              void* d_out, int out_size, void* d_ws, size_t ws_size,
                              hipStream_t stream) {
  const float* x_t    = (const float*)d_in[0];
  const float* h_prev = (const float*)d_in[1];
  const float* c_prev = (const float*)d_in[2];
  const float* ew     = (const float*)d_in[3];
  const int*   eidx   = (const int*)d_in[4];
  const float* Wi = (const float*)d_in[5];
  const float* Wf = (const float*)d_in[6];
  const float* Wc = (const float*)d_in[7];
  const float* Wo = (const float*)d_in[8];
  const float* Ti = (const float*)d_in[9];
  const float* Tf = (const float*)d_in[10];
  const float* Tc = (const float*)d_in[11];
  const float* To = (const float*)d_in[12];
  const float* bi = (const float*)d_in[13];
  const float* bf = (const float*)d_in[14];
  const float* bc = (const float*)d_in[15];
  const float* bo = (const float*)d_in[16];
  const float* wci = (const float*)d_in[17];
  const float* wcf = (const float*)d_in[18];
  const float* wco = (const float*)d_in[19];

  char* ws = (char*)d_ws;
  float* dinv  = (float*)(ws + 0);        // 200192
  int*   wscnt = (int*)(ws + 200192);     // 200192
  int*   off   = (int*)(ws + 400384);     // 200704
  int*   bsum  = (int*)(ws + 601088);     // 1024
  int*   boff  = (int*)(ws + 602112);     // 1024
  int2*  ed    = (int2*)(ws + 603136);    // 6400000
  unsigned short* bglob = (unsigned short*)(ws + 7003136);  // 524288

  char* outB = (char*)d_out;  // h-rows: [deg/cnt -> tx1b | hb]; c-rows: [segbase/rank -> tx2b | xb]
  float* h_out = (float*)d_out;
  float* c_out = h_out + (long)NN * 128;

  const int* esrc = eidx;
  const int* edst = eidx + EE;

  k_pre<<<KC + 32 + 782 + 782, 1024, 0, stream>>>(
      Wi, Wf, Wc, Wo, Ti, Tf, Tc, To, bglob, h_prev, x_t, outB, esrc, edst, ew);
  k_phase2<<<196, 256, 0, stream>>>(outB, dinv, wscnt, bsum);
  k_scan2<<<1, 256, 0, stream>>>(bsum, boff, 196);
  k_scan3<<<196, 256, 0, stream>>>(wscnt, boff, off);
  k_edge2<<<3125, 256, 0, stream>>>(esrc, edst, ew, dinv, off, outB, ed);
  k_gather<<<12500, 256, 0, stream>>>(outB + 256, nullptr, 1.f, off, ed, outB);
  k_gather<<<12500, 256, 0, stream>>>(outB, outB + 256, 2.f, off, ed,
                                      outB + (long)NN * 512);
  k_gemm<<<782, 256, 0, stream>>>(outB, bglob, c_prev,
                                  bi, bf, bc, bo, wci, wcf, wco, h_out, c_out);
}

// Round 9
// 210.329 us; speedup vs baseline: 1.7127x; 1.0738x over previous
//
#include <hip/hip_runtime.h>

#define NN 50000
#define EE 800000
#define KC 64          // histogram copies (one hist block each)
#define EPC (EE / KC)  // 12500 edges per hist block
#define DEG_SCALE 4096.0f

typedef float f32x4 __attribute__((ext_vector_type(4)));
typedef short bf16x8 __attribute__((ext_vector_type(8)));
typedef unsigned short u16x8 __attribute__((ext_vector_type(8)));

__device__ __forceinline__ unsigned short f2bf(float f) {
  unsigned int u = __float_as_uint(f);
  u += 0x7fffu + ((u >> 16) & 1u);
  return (unsigned short)(u >> 16);
}
__device__ __forceinline__ float bf2f(unsigned short u) {
  return __uint_as_float(((unsigned int)u) << 16);
}

__device__ __forceinline__ void async_copy16(const void* g, void* l) {
  __builtin_amdgcn_global_load_lds(
      (const __attribute__((address_space(1))) unsigned int*)g,
      (__attribute__((address_space(3))) unsigned int*)l, 16, 0, 0);
}

__device__ __forceinline__ float fast_sig(float x) {
  return __builtin_amdgcn_rcpf(1.f + __expf(-x));
}
__device__ __forceinline__ float fast_tanh(float x) {
  // 1 - 2/(e^{2x}+1): robust at +/-inf, rcp rel-err ~2^-22
  return 1.f - 2.f * __builtin_amdgcn_rcpf(__expf(2.f * x) + 1.f);
}

// ---- u16-slot scratch in the first 256B of each 512B d_out row ----
__device__ __forceinline__ unsigned short* hslot2(char* o, long j) {
  return (unsigned short*)(o + (j >> 7) * 512 + (j & 127) * 2);
}
__device__ __forceinline__ void store8u16(char* o, long s, uint4 v) {
  *(uint4*)(o + (s >> 7) * 512 + (s & 127) * 2) = v;  // s % 8 == 0
}
// h-region slots: deg copies [0, 3.2M) ; cnt copies [3.2M, 6.4M)
// c-region slots: segbase [0, 3.2M) ; rank [3.2M, 4.0M)
#define CNT_SLOT0 3200000L
#define RANK_SLOT0 3200000L

// ---------------- phase 1: LDS histograms + buildB + h->bf16 + x->bf16 ----------------
__global__ __launch_bounds__(1024) void k_pre(
    const float* __restrict__ Wi, const float* __restrict__ Wf,
    const float* __restrict__ Wc, const float* __restrict__ Wo,
    const float* __restrict__ Ti, const float* __restrict__ Tf,
    const float* __restrict__ Tc, const float* __restrict__ To,
    unsigned short* __restrict__ bglob, const float* __restrict__ h,
    const float* __restrict__ x, char* __restrict__ outB,
    const int* __restrict__ src, const int* __restrict__ dst,
    const float* __restrict__ w) {
  __shared__ unsigned hist[25000];  // 100 KB: packed 2 x u16 bins, all 50000 nodes
  const int b = blockIdx.x, tid = threadIdx.x;
  char* cB = outB + (long)NN * 512;
  if (b < KC) {
    uint4* h4 = (uint4*)hist;
    const int base = b * EPC;
    // ---- pass A: cnt (packed u16) + rank ----
    for (int j = tid; j < 6250; j += 1024) h4[j] = (uint4){0u, 0u, 0u, 0u};
    __syncthreads();
    for (int k = tid; k < EPC; k += 1024) {
      const int e = base + k;
      const int d = dst[e];
      const int sh = (d & 1) * 16;
      const unsigned old = atomicAdd(&hist[d >> 1], 1u << sh);
      *hslot2(cB, RANK_SLOT0 + e) = (unsigned short)((old >> sh) & 0xffffu);
    }
    __syncthreads();
    for (int j = tid; j < 6250; j += 1024)
      store8u16(outB, CNT_SLOT0 + (long)b * NN + j * 8, h4[j]);
    __syncthreads();
    // ---- pass B: deg (packed u16 fixed-point, scale 2^12) ----
    for (int j = tid; j < 6250; j += 1024) h4[j] = (uint4){0u, 0u, 0u, 0u};
    __syncthreads();
    for (int k = tid; k < EPC; k += 1024) {
      const int e = base + k;
      const int s = src[e];
      const unsigned q = (unsigned)__float2uint_rn(w[e] * DEG_SCALE);
      const int sh = (s & 1) * 16;
      atomicAdd(&hist[s >> 1], q << sh);
    }
    __syncthreads();
    for (int j = tid; j < 6250; j += 1024)
      store8u16(outB, (long)b * NN + j * 8, h4[j]);
  } else if (b < KC + 32) {
    // buildB: fragment-native
    const int t = (b - KC) * 1024 + tid;  // 0..32767
    const int ks = t >> 11;
    const int cf = (t >> 6) & 31;
    const int lane = t & 63;
    const int wv = cf >> 3, hl = (cf >> 2) & 1, g = cf & 3;
    const int kg = lane >> 4, lm = lane & 15;
    const int hc = (wv * 2 + hl) * 16 + lm;
    const float* Wg = (g == 0) ? Wi : (g == 1) ? Wf : (g == 2) ? Wc : Wo;
    const float* Tg = (g == 0) ? Ti : (g == 1) ? Tf : (g == 2) ? Tc : To;
    u16x8 out;
#pragma unroll
    for (int dk = 0; dk < 8; ++dk) {
      const int k = ks * 32 + kg * 8 + dk;
      const int kb = k >> 7, r = k & 127;
      const float v = (kb == 0) ? Wg[r * 128 + hc] : Tg[(kb - 1) * 16384 + r * 128 + hc];
      out[dk] = f2bf(v);
    }
    *(u16x8*)(bglob + t * 8) = out;
  } else if (b < KC + 32 + 782) {
    const int i = (b - (KC + 32)) * 1024 + tid;  // 8-f32 chunks of h
    if (i < 100000 * 8) {
      const float* hp = h + i * 8;
      const f32x4 v0 = *(const f32x4*)hp;
      const f32x4 v1 = *(const f32x4*)(hp + 4);
      u16x8 o;
#pragma unroll
      for (int e = 0; e < 4; ++e) o[e] = f2bf(v0[e]);
#pragma unroll
      for (int e = 0; e < 4; ++e) o[e + 4] = f2bf(v1[e]);
      *(u16x8*)(outB + (i >> 4) * 512 + 256 + (i & 15) * 16) = o;
    }
  } else {
    const int i = (b - (KC + 32 + 782)) * 1024 + tid;
    if (i < 100000 * 8) {
      const float* xp = x + i * 8;
      const f32x4 v0 = *(const f32x4*)xp;
      const f32x4 v1 = *(const f32x4*)(xp + 4);
      u16x8 o;
#pragma unroll
      for (int e = 0; e < 4; ++e) o[e] = f2bf(v0[e]);
#pragma unroll
      for (int e = 0; e < 4; ++e) o[e + 4] = f2bf(v1[e]);
      *(u16x8*)(cB + (i >> 4) * 512 + 256 + (i & 15) * 16) = o;
    }
  }
}

// ---------------- scan machinery ----------------
__device__ __forceinline__ int block_scan_excl_256(int v, int* total) {
  __shared__ int wsum[4];
  const int tid = threadIdx.x;
  const int lane = tid & 63, wv = tid >> 6;
  int x = v;
#pragma unroll
  for (int d = 1; d < 64; d <<= 1) {
    const int y = __shfl_up(x, d, 64);
    if (lane >= d) x += y;
  }
  if (lane == 63) wsum[wv] = x;
  __syncthreads();
  int pre = 0, tot = 0;
#pragma unroll
  for (int u = 0; u < 4; ++u) {
    const int s = wsum[u];
    pre += (u < wv) ? s : 0;
    tot += s;
  }
  *total = tot;
  return pre + x - v;
}

// reduce deg copies -> dinv; running-sum cnt copies -> segbase (c-region) + wscnt
__global__ void k_phase2(char* __restrict__ outB, float* __restrict__ dinv,
                         int* __restrict__ wscnt, int* __restrict__ bsum) {
  char* cB = outB + (long)NN * 512;
  const int i = blockIdx.x * 256 + threadIdx.x;
  int run = 0;
  if (i < NN) {
    float s = 0.f;
#pragma unroll
    for (int c = 0; c < KC; ++c)
      s += (float)*hslot2(outB, (long)c * NN + i);
    s *= (1.0f / DEG_SCALE);
    dinv[i] = (s > 0.f) ? rsqrtf(fmaxf(s, 1e-30f)) : 0.f;
#pragma unroll
    for (int c = 0; c < KC; ++c) {
      *hslot2(cB, (long)c * NN + i) = (unsigned short)run;
      run += (int)*hslot2(outB, CNT_SLOT0 + (long)c * NN + i);
    }
    wscnt[i] = run;
  }
  int tot;
  block_scan_excl_256(run, &tot);
  if (threadIdx.x == 0) bsum[blockIdx.x] = tot;
}

__global__ void k_scan2(const int* __restrict__ bsum, int* __restrict__ boff,
                        const int nb) {
  const int t = threadIdx.x;
  const int v = (t < nb) ? bsum[t] : 0;
  int tot;
  const int excl = block_scan_excl_256(v, &tot);
  if (t <= nb) boff[t] = excl;
}

__global__ void k_scan3(const int* __restrict__ cnt, const int* __restrict__ boff,
                        int* __restrict__ off) {
  const int i = blockIdx.x * 256 + threadIdx.x;
  const int v = (i < NN) ? cnt[i] : 0;
  int tot;
  const int excl = block_scan_excl_256(v, &tot) + boff[blockIdx.x];
  if (i < NN) off[i] = excl;
  if (i == NN) off[NN] = excl;
}

// atomic-free CSR fill: p = off[d] + segbase[copy][d] + rank[e]
__global__ void k_edge2(const int* __restrict__ src, const int* __restrict__ dst,
                        const float* __restrict__ w, const float* __restrict__ dinv,
                        const int* __restrict__ off, char* __restrict__ outB,
                        int2* __restrict__ ed) {
  const int e = blockIdx.x * blockDim.x + threadIdx.x;
  if (e >= EE) return;
  char* cB = outB + (long)NN * 512;
  const int s = src[e], d = dst[e];
  const int c = e / EPC;
  const int p = off[d] + (int)*hslot2(cB, (long)c * NN + d) +
                (int)*hslot2(cB, RANK_SLOT0 + e);
  int2 rec;
  rec.x = s;
  rec.y = __float_as_int(-w[e] * dinv[s] * dinv[d]);
  ed[p] = rec;
}

// ---------------- sparse gather (bf16 rows, 1 wave per node) ----------------
__global__ __launch_bounds__(256) void k_gather(
    const char* __restrict__ vinB, const char* __restrict__ vsubB, const float alpha,
    const int* __restrict__ off, const int2* __restrict__ ed, char* __restrict__ voutB) {
  const int wid = threadIdx.x >> 6, lane = threadIdx.x & 63;
  const int node = blockIdx.x * 4 + wid;
  const int p0 = off[node], p1 = off[node + 1];
  const int lb = lane * 4;
  float ax0 = 0.f, ay0 = 0.f, ax1 = 0.f, ay1 = 0.f;
  float ax2 = 0.f, ay2 = 0.f, ax3 = 0.f, ay3 = 0.f;
  int p = p0;
  for (; p + 7 < p1; p += 8) {
    int2 E[8];
    unsigned V[8];
#pragma unroll
    for (int u = 0; u < 8; ++u) E[u] = ed[p + u];
#pragma unroll
    for (int u = 0; u < 8; ++u)
      V[u] = *(const unsigned*)(vinB + (long)E[u].x * 512 + lb);
#pragma unroll
    for (int u = 0; u < 8; ++u) {
      const float wv = __int_as_float(E[u].y);
      float* ax = (u & 3) == 0 ? &ax0 : (u & 3) == 1 ? &ax1 : (u & 3) == 2 ? &ax2 : &ax3;
      float* ay = (u & 3) == 0 ? &ay0 : (u & 3) == 1 ? &ay1 : (u & 3) == 2 ? &ay2 : &ay3;
      *ax = fmaf(wv, bf2f((unsigned short)V[u]), *ax);
      *ay = fmaf(wv, bf2f((unsigned short)(V[u] >> 16)), *ay);
    }
  }
  for (; p + 3 < p1; p += 4) {
    const int2 e0 = ed[p], e1 = ed[p + 1], e2 = ed[p + 2], e3 = ed[p + 3];
    const unsigned v0 = *(const unsigned*)(vinB + (long)e0.x * 512 + lb);
    const unsigned v1 = *(const unsigned*)(vinB + (long)e1.x * 512 + lb);
    const unsigned v2 = *(const unsigned*)(vinB + (long)e2.x * 512 + lb);
    const unsigned v3 = *(const unsigned*)(vinB + (long)e3.x * 512 + lb);
    const float w0 = __int_as_float(e0.y), w1 = __int_as_float(e1.y);
    const float w2 = __int_as_float(e2.y), w3 = __int_as_float(e3.y);
    ax0 = fmaf(w0, bf2f((unsigned short)v0), ax0);
    ay0 = fmaf(w0, bf2f((unsigned short)(v0 >> 16)), ay0);
    ax1 = fmaf(w1, bf2f((unsigned short)v1), ax1);
    ay1 = fmaf(w1, bf2f((unsigned short)(v1 >> 16)), ay1);
    ax2 = fmaf(w2, bf2f((unsigned short)v2), ax2);
    ay2 = fmaf(w2, bf2f((unsigned short)(v2 >> 16)), ay2);
    ax3 = fmaf(w3, bf2f((unsigned short)v3), ax3);
    ay3 = fmaf(w3, bf2f((unsigned short)(v3 >> 16)), ay3);
  }
  for (; p < p1; ++p) {
    const int2 e0 = ed[p];
    const unsigned v0 = *(const unsigned*)(vinB + (long)e0.x * 512 + lb);
    const float w0 = __int_as_float(e0.y);
    ax0 = fmaf(w0, bf2f((unsigned short)v0), ax0);
    ay0 = fmaf(w0, bf2f((unsigned short)(v0 >> 16)), ay0);
  }
  float rx = alpha * ((ax0 + ax1) + (ax2 + ax3));
  float ry = alpha * ((ay0 + ay1) + (ay2 + ay3));
  if (vsubB) {
    const unsigned s = *(const unsigned*)(vsubB + (long)node * 512 + lb);
    rx -= bf2f((unsigned short)s);
    ry -= bf2f((unsigned short)(s >> 16));
  }
  const unsigned ow = (unsigned)f2bf(rx) | ((unsigned)f2bf(ry) << 16);
  *(unsigned*)(voutB + (long)node * 512 + lb) = ow;
}

// ---------------- dense stage: 8-wave blocks, cols split across waves ----------------
// A = [xb | hb | tx1b | tx2b] (64 rows x 512 bf16) staged ONCE into 64KB LDS
// (shared by all 8 waves); wave w owns hc band w*16+lm, ALL 4 gates (frag
// cf = w*4+g, since hc = (cf>>2)*16+lm by construction). acc = 16 f32x4/thread
// -> VGPR ~115, launch_bounds(512,4) -> 16 waves/CU. No in-loop barriers.
__global__ __launch_bounds__(512, 4) void k_gemm(
    const char* __restrict__ outB, const unsigned short* __restrict__ bglob,
    const float* __restrict__ c_prev,
    const float* __restrict__ b_i, const float* __restrict__ b_f,
    const float* __restrict__ b_c, const float* __restrict__ b_o,
    const float* __restrict__ w_ci, const float* __restrict__ w_cf,
    const float* __restrict__ w_co, float* __restrict__ h_out,
    float* __restrict__ c_out) {
  __shared__ char lds[65536];
  const int tid = threadIdx.x;
  const int lane = tid & 63;
  const int w = tid >> 6;       // wave 0..7 -> hc band
  const int kg = lane >> 4;
  const int lm = lane & 15;
  const int m0 = blockIdx.x * 64;

  const char* hB = outB;                   // +0: tx1b, +256: hb
  const char* cB = outB + (long)NN * 512;  // +0: tx2b, +256: xb

  // prologue: stage the whole A panel (16 k-tiles x 4KB), 8 gload_lds/thread
  {
    const int t8 = tid & 255;
    const int rf = t8 >> 6, ln = t8 & 63;
    const int srow0 = m0 + rf * 16 + (ln & 15);
    const long srow = (srow0 < NN) ? srow0 : (NN - 1);
    const int schunk = (ln >> 4) * 16;
#pragma unroll
    for (int i = 0; i < 8; ++i) {
      const int ks = i * 2 + (tid >> 8);
      const char* base = (ks < 4) ? (cB + 256) : (ks < 8) ? (hB + 256) : (ks < 12) ? hB : cB;
      async_copy16(base + srow * 512 + (ks & 3) * 64 + schunk,
                   &lds[ks * 4096 + t8 * 16]);
    }
  }

  f32x4 acc[16];  // acc[rf*4 + g]
#pragma unroll
  for (int i = 0; i < 16; ++i) acc[i] = (f32x4){0.f, 0.f, 0.f, 0.f};

  bf16x8 b0[4], b1[4];
  auto loadB = [&](int ks, bf16x8* bb) {
    const unsigned short* fp = bglob + ((ks * 32 + w * 4) * 64 + lane) * 8;
#pragma unroll
    for (int g = 0; g < 4; ++g) bb[g] = *(const bf16x8*)(fp + g * 512);
  };

  __syncthreads();  // A panel resident after this; LDS is read-only below

  loadB(0, b0);
#pragma unroll
  for (int ks = 0; ks < 16; ++ks) {
    bf16x8* bc = (ks & 1) ? b1 : b0;
    bf16x8* bn = (ks & 1) ? b0 : b1;
    if (ks < 15) loadB(ks + 1, bn);
    bf16x8 a[4];
#pragma unroll
    for (int rf = 0; rf < 4; ++rf)
      a[rf] = *(const bf16x8*)(&lds[ks * 4096 + rf * 1024 + lane * 16]);
#pragma unroll
    for (int rf = 0; rf < 4; ++rf)
#pragma unroll
      for (int g = 0; g < 4; ++g)
        acc[rf * 4 + g] =
            __builtin_amdgcn_mfma_f32_16x16x32_bf16(a[rf], bc[g], acc[rf * 4 + g], 0, 0, 0);
  }

  // Epilogue: hc = w*16+lm fixed per thread; node = m0+rf*16+kg*4+reg
  const int hc = w * 16 + lm;
  const float bi = b_i[hc], bfv = b_f[hc], bc_ = b_c[hc], bo = b_o[hc];
  const float wci = w_ci[hc], wcf = w_cf[hc], wco = w_co[hc];
#pragma unroll
  for (int rf = 0; rf < 4; ++rf) {
#pragma unroll
    for (int reg = 0; reg < 4; ++reg) {
      const int node = m0 + rf * 16 + kg * 4 + reg;
      if (node < NN) {
        const float cp = c_prev[node * 128 + hc];
        const float pi = acc[rf * 4 + 0][reg] + bi + wci * cp;
        const float pf = acc[rf * 4 + 1][reg] + bfv + wcf * cp;
        const float pc = acc[rf * 4 + 2][reg] + bc_;
        const float po = acc[rf * 4 + 3][reg] + bo;
        const float ig = fast_sig(pi);
        const float fg = fast_sig(pf);
        const float ct = fg * cp + ig * fast_tanh(pc);
        const float og = fast_sig(po + wco * ct);
        h_out[node * 128 + hc] = og * fast_tanh(ct);
        c_out[node * 128 + hc] = ct;
      }
    }
  }
}

// ---------------- launcher ----------------

extern "C" void kernel_launch(void* const* d_in, const int* in_sizes, int n_in,
                              void* d_out, int out_size, void* d_ws, size_t ws_size,
                              hipStream_t stream) {
  const float* x_t    = (const float*)d_in[0];
  const float* h_prev = (const float*)d_in[1];
  const float* c_prev = (const float*)d_in[2];
  const float* ew     = (const float*)d_in[3];
  const int*   eidx   = (const int*)d_in[4];
  const float* Wi = (const float*)d_in[5];
  const float* Wf = (const float*)d_in[6];
  const float* Wc = (const float*)d_in[7];
  const float* Wo = (const float*)d_in[8];
  const float* Ti = (const float*)d_in[9];
  const float* Tf = (const float*)d_in[10];
  const float* Tc = (const float*)d_in[11];
  const float* To = (const float*)d_in[12];
  const float* bi = (const float*)d_in[13];
  const float* bf = (const float*)d_in[14];
  const float* bc = (const float*)d_in[15];
  const float* bo = (const float*)d_in[16];
  const float* wci = (const float*)d_in[17];
  const float* wcf = (const float*)d_in[18];
  const float* wco = (const float*)d_in[19];

  char* ws = (char*)d_ws;
  float* dinv  = (float*)(ws + 0);        // 200192
  int*   wscnt = (int*)(ws + 200192);     // 200192
  int*   off   = (int*)(ws + 400384);     // 200704
  int*   bsum  = (int*)(ws + 601088);     // 1024
  int*   boff  = (int*)(ws + 602112);     // 1024
  int2*  ed    = (int2*)(ws + 603136);    // 6400000
  unsigned short* bglob = (unsigned short*)(ws + 7003136);  // 524288

  char* outB = (char*)d_out;  // h-rows: [deg/cnt -> tx1b | hb]; c-rows: [segbase/rank -> tx2b | xb]
  float* h_out = (float*)d_out;
  float* c_out = h_out + (long)NN * 128;

  const int* esrc = eidx;
  const int* edst = eidx + EE;

  k_pre<<<KC + 32 + 782 + 782, 1024, 0, stream>>>(
      Wi, Wf, Wc, Wo, Ti, Tf, Tc, To, bglob, h_prev, x_t, outB, esrc, edst, ew);
  k_phase2<<<196, 256, 0, stream>>>(outB, dinv, wscnt, bsum);
  k_scan2<<<1, 256, 0, stream>>>(bsum, boff, 196);
  k_scan3<<<196, 256, 0, stream>>>(wscnt, boff, off);
  k_edge2<<<3125, 256, 0, stream>>>(esrc, edst, ew, dinv, off, outB, ed);
  k_gather<<<12500, 256, 0, stream>>>(outB + 256, nullptr, 1.f, off, ed, outB);
  k_gather<<<12500, 256, 0, stream>>>(outB, outB + 256, 2.f, off, ed,
                                      outB + (long)NN * 512);
  k_gemm<<<782, 512, 0, stream>>>(outB, bglob, c_prev,
                                  bi, bf, bc, bo, wci, wcf, wco, h_out, c_out);
}

// Round 10
// 197.172 us; speedup vs baseline: 1.8270x; 1.0667x over previous
//
#include <hip/hip_runtime.h>

#define NN 50000
#define EE 800000
#define KC 64          // histogram copies (one hist block each)
#define EPC (EE / KC)  // 12500 edges per hist block
#define DEG_SCALE 4096.0f

typedef float f32x4 __attribute__((ext_vector_type(4)));
typedef short bf16x8 __attribute__((ext_vector_type(8)));
typedef unsigned short u16x8 __attribute__((ext_vector_type(8)));

__device__ __forceinline__ unsigned short f2bf(float f) {
  unsigned int u = __float_as_uint(f);
  u += 0x7fffu + ((u >> 16) & 1u);
  return (unsigned short)(u >> 16);
}
__device__ __forceinline__ float bf2f(unsigned short u) {
  return __uint_as_float(((unsigned int)u) << 16);
}

__device__ __forceinline__ void async_copy16(const void* g, void* l) {
  __builtin_amdgcn_global_load_lds(
      (const __attribute__((address_space(1))) unsigned int*)g,
      (__attribute__((address_space(3))) unsigned int*)l, 16, 0, 0);
}

__device__ __forceinline__ float fast_sig(float x) {
  return __builtin_amdgcn_rcpf(1.f + __expf(-x));
}
__device__ __forceinline__ float fast_tanh(float x) {
  return 1.f - 2.f * __builtin_amdgcn_rcpf(__expf(2.f * x) + 1.f);
}

// ---- u16-slot scratch in the first 256B of each 512B d_out row ----
__device__ __forceinline__ unsigned short* hslot2(char* o, long j) {
  return (unsigned short*)(o + (j >> 7) * 512 + (j & 127) * 2);
}
__device__ __forceinline__ void store8u16(char* o, long s, uint4 v) {
  *(uint4*)(o + (s >> 7) * 512 + (s & 127) * 2) = v;  // s % 8 == 0
}
// h-region slots: deg copies [0, 3.2M) ; cnt copies [3.2M, 6.4M)
// c-region slots: segbase [0, 3.2M) ; rank [3.2M, 4.0M)
#define CNT_SLOT0 3200000L
#define RANK_SLOT0 3200000L

// ---------------- phase 1: LDS histograms + buildB + h->bf16 + x->bf16 ----------------
__global__ __launch_bounds__(1024) void k_pre(
    const float* __restrict__ Wi, const float* __restrict__ Wf,
    const float* __restrict__ Wc, const float* __restrict__ Wo,
    const float* __restrict__ Ti, const float* __restrict__ Tf,
    const float* __restrict__ Tc, const float* __restrict__ To,
    unsigned short* __restrict__ bglob, const float* __restrict__ h,
    const float* __restrict__ x, char* __restrict__ outB,
    const int* __restrict__ src, const int* __restrict__ dst,
    const float* __restrict__ w) {
  __shared__ unsigned hist[25000];  // 100 KB: packed 2 x u16 bins, all 50000 nodes
  const int b = blockIdx.x, tid = threadIdx.x;
  char* cB = outB + (long)NN * 512;
  if (b < KC) {
    uint4* h4 = (uint4*)hist;
    const int base = b * EPC;
    // ---- pass A: cnt (packed u16) + rank ----
    for (int j = tid; j < 6250; j += 1024) h4[j] = (uint4){0u, 0u, 0u, 0u};
    __syncthreads();
    for (int k = tid; k < EPC; k += 1024) {
      const int e = base + k;
      const int d = dst[e];
      const int sh = (d & 1) * 16;
      const unsigned old = atomicAdd(&hist[d >> 1], 1u << sh);
      *hslot2(cB, RANK_SLOT0 + e) = (unsigned short)((old >> sh) & 0xffffu);
    }
    __syncthreads();
    for (int j = tid; j < 6250; j += 1024)
      store8u16(outB, CNT_SLOT0 + (long)b * NN + j * 8, h4[j]);
    __syncthreads();
    // ---- pass B: deg (packed u16 fixed-point, scale 2^12) ----
    for (int j = tid; j < 6250; j += 1024) h4[j] = (uint4){0u, 0u, 0u, 0u};
    __syncthreads();
    for (int k = tid; k < EPC; k += 1024) {
      const int e = base + k;
      const int s = src[e];
      const unsigned q = (unsigned)__float2uint_rn(w[e] * DEG_SCALE);
      const int sh = (s & 1) * 16;
      atomicAdd(&hist[s >> 1], q << sh);
    }
    __syncthreads();
    for (int j = tid; j < 6250; j += 1024)
      store8u16(outB, (long)b * NN + j * 8, h4[j]);
  } else if (b < KC + 32) {
    // buildB: fragment-native
    const int t = (b - KC) * 1024 + tid;  // 0..32767
    const int ks = t >> 11;
    const int cf = (t >> 6) & 31;
    const int lane = t & 63;
    const int wv = cf >> 3, hl = (cf >> 2) & 1, g = cf & 3;
    const int kg = lane >> 4, lm = lane & 15;
    const int hc = (wv * 2 + hl) * 16 + lm;
    const float* Wg = (g == 0) ? Wi : (g == 1) ? Wf : (g == 2) ? Wc : Wo;
    const float* Tg = (g == 0) ? Ti : (g == 1) ? Tf : (g == 2) ? Tc : To;
    u16x8 out;
#pragma unroll
    for (int dk = 0; dk < 8; ++dk) {
      const int k = ks * 32 + kg * 8 + dk;
      const int kb = k >> 7, r = k & 127;
      const float v = (kb == 0) ? Wg[r * 128 + hc] : Tg[(kb - 1) * 16384 + r * 128 + hc];
      out[dk] = f2bf(v);
    }
    *(u16x8*)(bglob + t * 8) = out;
  } else if (b < KC + 32 + 782) {
    const int i = (b - (KC + 32)) * 1024 + tid;  // 8-f32 chunks of h
    if (i < 100000 * 8) {
      const float* hp = h + i * 8;
      const f32x4 v0 = *(const f32x4*)hp;
      const f32x4 v1 = *(const f32x4*)(hp + 4);
      u16x8 o;
#pragma unroll
      for (int e = 0; e < 4; ++e) o[e] = f2bf(v0[e]);
#pragma unroll
      for (int e = 0; e < 4; ++e) o[e + 4] = f2bf(v1[e]);
      *(u16x8*)(outB + (i >> 4) * 512 + 256 + (i & 15) * 16) = o;
    }
  } else {
    const int i = (b - (KC + 32 + 782)) * 1024 + tid;
    if (i < 100000 * 8) {
      const float* xp = x + i * 8;
      const f32x4 v0 = *(const f32x4*)xp;
      const f32x4 v1 = *(const f32x4*)(xp + 4);
      u16x8 o;
#pragma unroll
      for (int e = 0; e < 4; ++e) o[e] = f2bf(v0[e]);
#pragma unroll
      for (int e = 0; e < 4; ++e) o[e + 4] = f2bf(v1[e]);
      *(u16x8*)(cB + (i >> 4) * 512 + 256 + (i & 15) * 16) = o;
    }
  }
}

// ---------------- phase 2: wave-per-node copy reduction/scan ----------------
// Wave handles node i; lane c owns copy c. segbase = exclusive wave-scan of cnt,
// dinv from butterfly-reduced fixed-point deg. 12500 blocks x 4 waves.
__global__ __launch_bounds__(256) void k_phase2(char* __restrict__ outB,
                                                float* __restrict__ dinv,
                                                int* __restrict__ wscnt) {
  char* cB = outB + (long)NN * 512;
  const int lane = threadIdx.x & 63;  // copy index c
  const int i = blockIdx.x * 4 + (threadIdx.x >> 6);
  const int c = lane;
  const int cnt_c = (int)*hslot2(outB, CNT_SLOT0 + (long)c * NN + i);
  const float deg_c = (float)*hslot2(outB, (long)c * NN + i);
  // exclusive scan of cnt over lanes
  int x = cnt_c;
#pragma unroll
  for (int d = 1; d < 64; d <<= 1) {
    const int y = __shfl_up(x, d, 64);
    if (lane >= d) x += y;
  }
  *hslot2(cB, (long)c * NN + i) = (unsigned short)(x - cnt_c);
  // butterfly reduce deg
  float s = deg_c;
#pragma unroll
  for (int d = 1; d < 64; d <<= 1) s += __shfl_xor(s, d, 64);
  if (lane == 0) {
    s *= (1.0f / DEG_SCALE);
    dinv[i] = (s > 0.f) ? rsqrtf(fmaxf(s, 1e-30f)) : 0.f;
  }
  if (lane == 63) wscnt[i] = x;  // inclusive total
}

// ---------------- scan machinery ----------------
__device__ __forceinline__ int block_scan_excl_256(int v, int* total) {
  __shared__ int wsum[4];
  const int tid = threadIdx.x;
  const int lane = tid & 63, wv = tid >> 6;
  int x = v;
#pragma unroll
  for (int d = 1; d < 64; d <<= 1) {
    const int y = __shfl_up(x, d, 64);
    if (lane >= d) x += y;
  }
  if (lane == 63) wsum[wv] = x;
  __syncthreads();
  int pre = 0, tot = 0;
#pragma unroll
  for (int u = 0; u < 4; ++u) {
    const int s = wsum[u];
    pre += (u < wv) ? s : 0;
    tot += s;
  }
  *total = tot;
  return pre + x - v;
}

__global__ void k_scan1(const int* __restrict__ wscnt, int* __restrict__ bsum) {
  const int i = blockIdx.x * 256 + threadIdx.x;
  const int v = (i < NN) ? wscnt[i] : 0;
  int tot;
  block_scan_excl_256(v, &tot);
  if (threadIdx.x == 0) bsum[blockIdx.x] = tot;
}

__global__ void k_scan2(const int* __restrict__ bsum, int* __restrict__ boff,
                        const int nb) {
  const int t = threadIdx.x;
  const int v = (t < nb) ? bsum[t] : 0;
  int tot;
  const int excl = block_scan_excl_256(v, &tot);
  if (t <= nb) boff[t] = excl;
}

__global__ void k_scan3(const int* __restrict__ cnt, const int* __restrict__ boff,
                        int* __restrict__ off) {
  const int i = blockIdx.x * 256 + threadIdx.x;
  const int v = (i < NN) ? cnt[i] : 0;
  int tot;
  const int excl = block_scan_excl_256(v, &tot) + boff[blockIdx.x];
  if (i < NN) off[i] = excl;
  if (i == NN) off[NN] = excl;
}

// atomic-free CSR fill: p = off[d] + segbase[copy][d] + rank[e]
__global__ void k_edge2(const int* __restrict__ src, const int* __restrict__ dst,
                        const float* __restrict__ w, const float* __restrict__ dinv,
                        const int* __restrict__ off, char* __restrict__ outB,
                        int2* __restrict__ ed) {
  const int e = blockIdx.x * blockDim.x + threadIdx.x;
  if (e >= EE) return;
  char* cB = outB + (long)NN * 512;
  const int s = src[e], d = dst[e];
  const int c = e / EPC;
  const int p = off[d] + (int)*hslot2(cB, (long)c * NN + d) +
                (int)*hslot2(cB, RANK_SLOT0 + e);
  int2 rec;
  rec.x = s;
  rec.y = __float_as_int(-w[e] * dinv[s] * dinv[d]);
  ed[p] = rec;
}

// ---------------- sparse gather (bf16 rows, 1 wave per node) ----------------
__global__ __launch_bounds__(256) void k_gather(
    const char* __restrict__ vinB, const char* __restrict__ vsubB, const float alpha,
    const int* __restrict__ off, const int2* __restrict__ ed, char* __restrict__ voutB) {
  const int wid = threadIdx.x >> 6, lane = threadIdx.x & 63;
  const int node = blockIdx.x * 4 + wid;
  const int p0 = off[node], p1 = off[node + 1];
  const int lb = lane * 4;
  float ax0 = 0.f, ay0 = 0.f, ax1 = 0.f, ay1 = 0.f;
  float ax2 = 0.f, ay2 = 0.f, ax3 = 0.f, ay3 = 0.f;
  int p = p0;
  for (; p + 7 < p1; p += 8) {
    int2 E[8];
    unsigned V[8];
#pragma unroll
    for (int u = 0; u < 8; ++u) E[u] = ed[p + u];
#pragma unroll
    for (int u = 0; u < 8; ++u)
      V[u] = *(const unsigned*)(vinB + (long)E[u].x * 512 + lb);
#pragma unroll
    for (int u = 0; u < 8; ++u) {
      const float wv = __int_as_float(E[u].y);
      float* ax = (u & 3) == 0 ? &ax0 : (u & 3) == 1 ? &ax1 : (u & 3) == 2 ? &ax2 : &ax3;
      float* ay = (u & 3) == 0 ? &ay0 : (u & 3) == 1 ? &ay1 : (u & 3) == 2 ? &ay2 : &ay3;
      *ax = fmaf(wv, bf2f((unsigned short)V[u]), *ax);
      *ay = fmaf(wv, bf2f((unsigned short)(V[u] >> 16)), *ay);
    }
  }
  for (; p + 3 < p1; p += 4) {
    const int2 e0 = ed[p], e1 = ed[p + 1], e2 = ed[p + 2], e3 = ed[p + 3];
    const unsigned v0 = *(const unsigned*)(vinB + (long)e0.x * 512 + lb);
    const unsigned v1 = *(const unsigned*)(vinB + (long)e1.x * 512 + lb);
    const unsigned v2 = *(const unsigned*)(vinB + (long)e2.x * 512 + lb);
    const unsigned v3 = *(const unsigned*)(vinB + (long)e3.x * 512 + lb);
    const float w0 = __int_as_float(e0.y), w1 = __int_as_float(e1.y);
    const float w2 = __int_as_float(e2.y), w3 = __int_as_float(e3.y);
    ax0 = fmaf(w0, bf2f((unsigned short)v0), ax0);
    ay0 = fmaf(w0, bf2f((unsigned short)(v0 >> 16)), ay0);
    ax1 = fmaf(w1, bf2f((unsigned short)v1), ax1);
    ay1 = fmaf(w1, bf2f((unsigned short)(v1 >> 16)), ay1);
    ax2 = fmaf(w2, bf2f((unsigned short)v2), ax2);
    ay2 = fmaf(w2, bf2f((unsigned short)(v2 >> 16)), ay2);
    ax3 = fmaf(w3, bf2f((unsigned short)v3), ax3);
    ay3 = fmaf(w3, bf2f((unsigned short)(v3 >> 16)), ay3);
  }
  for (; p < p1; ++p) {
    const int2 e0 = ed[p];
    const unsigned v0 = *(const unsigned*)(vinB + (long)e0.x * 512 + lb);
    const float w0 = __int_as_float(e0.y);
    ax0 = fmaf(w0, bf2f((unsigned short)v0), ax0);
    ay0 = fmaf(w0, bf2f((unsigned short)(v0 >> 16)), ay0);
  }
  float rx = alpha * ((ax0 + ax1) + (ax2 + ax3));
  float ry = alpha * ((ay0 + ay1) + (ay2 + ay3));
  if (vsubB) {
    const unsigned s = *(const unsigned*)(vsubB + (long)node * 512 + lb);
    rx -= bf2f((unsigned short)s);
    ry -= bf2f((unsigned short)(s >> 16));
  }
  const unsigned ow = (unsigned)f2bf(rx) | ((unsigned)f2bf(ry) << 16);
  *(unsigned*)(voutB + (long)node * 512 + lb) = ow;
}

// ---------------- dense stage: 8-wave blocks, depth-3 B pipeline ----------------
__global__ __launch_bounds__(512, 4) void k_gemm(
    const char* __restrict__ outB, const unsigned short* __restrict__ bglob,
    const float* __restrict__ c_prev,
    const float* __restrict__ b_i, const float* __restrict__ b_f,
    const float* __restrict__ b_c, const float* __restrict__ b_o,
    const float* __restrict__ w_ci, const float* __restrict__ w_cf,
    const float* __restrict__ w_co, float* __restrict__ h_out,
    float* __restrict__ c_out) {
  __shared__ char lds[65536];
  const int tid = threadIdx.x;
  const int lane = tid & 63;
  const int w = tid >> 6;       // wave 0..7 -> hc band
  const int kg = lane >> 4;
  const int lm = lane & 15;
  const int m0 = blockIdx.x * 64;

  const char* hB = outB;                   // +0: tx1b, +256: hb
  const char* cB = outB + (long)NN * 512;  // +0: tx2b, +256: xb

  // prologue: stage the whole A panel (16 k-tiles x 4KB), 8 gload_lds/thread
  {
    const int t8 = tid & 255;
    const int rf = t8 >> 6, ln = t8 & 63;
    const int srow0 = m0 + rf * 16 + (ln & 15);
    const long srow = (srow0 < NN) ? srow0 : (NN - 1);
    const int schunk = (ln >> 4) * 16;
#pragma unroll
    for (int i = 0; i < 8; ++i) {
      const int ks = i * 2 + (tid >> 8);
      const char* base = (ks < 4) ? (cB + 256) : (ks < 8) ? (hB + 256) : (ks < 12) ? hB : cB;
      async_copy16(base + srow * 512 + (ks & 3) * 64 + schunk,
                   &lds[ks * 4096 + t8 * 16]);
    }
  }

  f32x4 acc[16];  // acc[rf*4 + g]
#pragma unroll
  for (int i = 0; i < 16; ++i) acc[i] = (f32x4){0.f, 0.f, 0.f, 0.f};

  bf16x8 B[3][4];
  auto loadB = [&](int ks, bf16x8* bb) {
    const unsigned short* fp = bglob + ((ks * 32 + w * 4) * 64 + lane) * 8;
#pragma unroll
    for (int g = 0; g < 4; ++g) bb[g] = *(const bf16x8*)(fp + g * 512);
  };

  // issue first 3 B tiles before the barrier: overlap with A-stage drain
  loadB(0, B[0]);
  loadB(1, B[1]);
  loadB(2, B[2]);

  __syncthreads();  // A panel resident after this; LDS is read-only below

#pragma unroll
  for (int ks = 0; ks < 16; ++ks) {
    const int m = ks % 3;
    bf16x8 a[4];
#pragma unroll
    for (int rf = 0; rf < 4; ++rf)
      a[rf] = *(const bf16x8*)(&lds[ks * 4096 + rf * 1024 + lane * 16]);
#pragma unroll
    for (int rf = 0; rf < 4; ++rf)
#pragma unroll
      for (int g = 0; g < 4; ++g)
        acc[rf * 4 + g] =
            __builtin_amdgcn_mfma_f32_16x16x32_bf16(a[rf], B[m][g], acc[rf * 4 + g], 0, 0, 0);
    if (ks + 3 < 16) loadB(ks + 3, B[m]);  // refill just-consumed buffer
  }

  // Epilogue: hc = w*16+lm fixed per thread; node = m0+rf*16+kg*4+reg
  const int hc = w * 16 + lm;
  const float bi = b_i[hc], bfv = b_f[hc], bc_ = b_c[hc], bo = b_o[hc];
  const float wci = w_ci[hc], wcf = w_cf[hc], wco = w_co[hc];
#pragma unroll
  for (int rf = 0; rf < 4; ++rf) {
#pragma unroll
    for (int reg = 0; reg < 4; ++reg) {
      const int node = m0 + rf * 16 + kg * 4 + reg;
      if (node < NN) {
        const float cp = c_prev[node * 128 + hc];
        const float pi = acc[rf * 4 + 0][reg] + bi + wci * cp;
        const float pf = acc[rf * 4 + 1][reg] + bfv + wcf * cp;
        const float pc = acc[rf * 4 + 2][reg] + bc_;
        const float po = acc[rf * 4 + 3][reg] + bo;
        const float ig = fast_sig(pi);
        const float fg = fast_sig(pf);
        const float ct = fg * cp + ig * fast_tanh(pc);
        const float og = fast_sig(po + wco * ct);
        h_out[node * 128 + hc] = og * fast_tanh(ct);
        c_out[node * 128 + hc] = ct;
      }
    }
  }
}

// ---------------- launcher ----------------

extern "C" void kernel_launch(void* const* d_in, const int* in_sizes, int n_in,
                              void* d_out, int out_size, void* d_ws, size_t ws_size,
                              hipStream_t stream) {
  const float* x_t    = (const float*)d_in[0];
  const float* h_prev = (const float*)d_in[1];
  const float* c_prev = (const float*)d_in[2];
  const float* ew     = (const float*)d_in[3];
  const int*   eidx   = (const int*)d_in[4];
  const float* Wi = (const float*)d_in[5];
  const float* Wf = (const float*)d_in[6];
  const float* Wc = (const float*)d_in[7];
  const float* Wo = (const float*)d_in[8];
  const float* Ti = (const float*)d_in[9];
  const float* Tf = (const float*)d_in[10];
  const float* Tc = (const float*)d_in[11];
  const float* To = (const float*)d_in[12];
  const float* bi = (const float*)d_in[13];
  const float* bf = (const float*)d_in[14];
  const float* bc = (const float*)d_in[15];
  const float* bo = (const float*)d_in[16];
  const float* wci = (const float*)d_in[17];
  const float* wcf = (const float*)d_in[18];
  const float* wco = (const float*)d_in[19];

  char* ws = (char*)d_ws;
  float* dinv  = (float*)(ws + 0);        // 200192
  int*   wscnt = (int*)(ws + 200192);     // 200192
  int*   off   = (int*)(ws + 400384);     // 200704
  int*   bsum  = (int*)(ws + 601088);     // 1024
  int*   boff  = (int*)(ws + 602112);     // 1024
  int2*  ed    = (int2*)(ws + 603136);    // 6400000
  unsigned short* bglob = (unsigned short*)(ws + 7003136);  // 524288

  char* outB = (char*)d_out;  // h-rows: [deg/cnt -> tx1b | hb]; c-rows: [segbase/rank -> tx2b | xb]
  float* h_out = (float*)d_out;
  float* c_out = h_out + (long)NN * 128;

  const int* esrc = eidx;
  const int* edst = eidx + EE;

  k_pre<<<KC + 32 + 782 + 782, 1024, 0, stream>>>(
      Wi, Wf, Wc, Wo, Ti, Tf, Tc, To, bglob, h_prev, x_t, outB, esrc, edst, ew);
  k_phase2<<<12500, 256, 0, stream>>>(outB, dinv, wscnt);
  k_scan1<<<196, 256, 0, stream>>>(wscnt, bsum);
  k_scan2<<<1, 256, 0, stream>>>(bsum, boff, 196);
  k_scan3<<<196, 256, 0, stream>>>(wscnt, boff, off);
  k_edge2<<<3125, 256, 0, stream>>>(esrc, edst, ew, dinv, off, outB, ed);
  k_gather<<<12500, 256, 0, stream>>>(outB + 256, nullptr, 1.f, off, ed, outB);
  k_gather<<<12500, 256, 0, stream>>>(outB, outB + 256, 2.f, off, ed,
                                      outB + (long)NN * 512);
  k_gemm<<<782, 512, 0, stream>>>(outB, bglob, c_prev,
                                  bi, bf, bc, bo, wci, wcf, wco, h_out, c_out);
}